// Round 7
// baseline (193.317 us; speedup 1.0000x reference)
//
#include <hip/hip_runtime.h>

#define BATCH 4
#define SEQ   4096
#define CDIM  1024
#define DDIM  64
#define NROW  (BATCH * SEQ)   // 16384
#define SPA   70              // attn LDS stride (f16)
#define NSPL  8

typedef _Float16 f16;
typedef _Float16 f16x8 __attribute__((ext_vector_type(8)));
typedef _Float16 f16x4 __attribute__((ext_vector_type(4)));
typedef __fp16   h16x2 __attribute__((ext_vector_type(2)));  // cvt_pkrtz return type
typedef float    f32x4 __attribute__((ext_vector_type(4)));

#define MFMA32(a, b, c) __builtin_amdgcn_mfma_f32_16x16x32_f16((a), (b), (c), 0, 0, 0)
#define MFMA16(a, b, c) __builtin_amdgcn_mfma_f32_16x16x16f16((a), (b), (c), 0, 0, 0)

// scores = (q·k)*8 (the /scale bug); softmax in exp2 domain => fold 8*log2(e) into q
#define QSCALE 11.5415603f

__device__ inline f16x8 cvt8(f32x4 a, f32x4 b) {
  h16x2 p0 = __builtin_amdgcn_cvt_pkrtz(a[0], a[1]);
  h16x2 p1 = __builtin_amdgcn_cvt_pkrtz(a[2], a[3]);
  h16x2 p2 = __builtin_amdgcn_cvt_pkrtz(b[0], b[1]);
  h16x2 p3 = __builtin_amdgcn_cvt_pkrtz(b[2], b[3]);
  f16x8 r;
  r[0] = p0[0]; r[1] = p0[1]; r[2] = p1[0]; r[3] = p1[1];
  r[4] = p2[0]; r[5] = p2[1]; r[6] = p3[0]; r[7] = p3[1];
  return r;
}

__device__ inline f16x4 cvt4(float a, float b, float c, float d) {
  h16x2 lo = __builtin_amdgcn_cvt_pkrtz(a, b);
  h16x2 hi = __builtin_amdgcn_cvt_pkrtz(c, d);
  f16x4 r;
  r[0] = lo[0]; r[1] = lo[1]; r[2] = hi[0]; r[3] = hi[1];
  return r;
}

// ---------------- W fp32 -> f16 prep (once; proj re-reads f16 from L2) --------
__global__ __launch_bounds__(256) void prep_w_kernel(const float* __restrict__ Wq,
                                                     const float* __restrict__ Wk,
                                                     const float* __restrict__ Wv,
                                                     f16* __restrict__ wf) {
  const int i = (blockIdx.x * 256 + threadIdx.x) * 4;  // 64 blocks cover 65536
  f32x4 a = *(const f32x4*)(Wq + i);
  f32x4 b = *(const f32x4*)(Wk + i);
  f32x4 c = *(const f32x4*)(Wv + i);
  *(f16x4*)(wf + i)          = cvt4(a[0], a[1], a[2], a[3]);
  *(f16x4*)(wf + 65536 + i)  = cvt4(b[0], b[1], b[2], b[3]);
  *(f16x4*)(wf + 131072 + i) = cvt4(c[0], c[1], c[2], c[3]);
}

// ---------------- fused QKV projection: barrier-free K-split GEMM -------------
// 512 blocks x 4 waves. Wave (p = w&1, kh = w>>1): rows [blk*32+p*16, +16),
// channels [kh*512, +512), all 192 output cols. W B-frags read directly from
// L2 (wf is 384 KB, chip-resident); x streamed from HBM. NO barriers in the
// K-loop -> waves free-run, compiler software-pipelines the unrolled loop.
// K halves combined through LDS once at the end.
__global__ __launch_bounds__(256, 2) void proj_kernel(const float* __restrict__ x,
                                                      const f16* __restrict__ wf,
                                                      const float* __restrict__ bq,
                                                      const float* __restrict__ bk,
                                                      const float* __restrict__ bv,
                                                      f16* __restrict__ qs,
                                                      f16* __restrict__ ks,
                                                      f16* __restrict__ vT) {
  __shared__ __attribute__((aligned(16))) f32x4 comb[2][64][12];  // 24 KB
  const int tid = threadIdx.x, lane = tid & 63, w = tid >> 6;
  const int n = lane & 15, quad = lane >> 4;
  const int p = w & 1;    // row half
  const int kh = w >> 1;  // channel (K) half
  const int row0 = blockIdx.x * 32 + p * 16;

  f32x4 acc[3][4];
#pragma unroll
  for (int m_ = 0; m_ < 3; ++m_)
#pragma unroll
    for (int t_ = 0; t_ < 4; ++t_) acc[m_][t_] = (f32x4){0.f, 0.f, 0.f, 0.f};

  const float* xp = x + (size_t)(row0 + n) * CDIM + kh * 512 + quad * 8;
  const f16* wp = wf + (size_t)n * CDIM + kh * 512 + quad * 8;

#pragma unroll 4
  for (int c = 0; c < 512; c += 32) {
    const f32x4 x0 = *(const f32x4*)(xp + c);
    const f32x4 x1 = *(const f32x4*)(xp + c + 4);
    const f16x8 a = cvt8(x0, x1);
#pragma unroll
    for (int mat = 0; mat < 3; ++mat)
#pragma unroll
      for (int tile = 0; tile < 4; ++tile) {
        const f16x8 bf = *(const f16x8*)(wp + (size_t)(mat * 64 + tile * 16) * CDIM + c);
        acc[mat][tile] = MFMA32(a, bf, acc[mat][tile]);
      }
  }

  // combine K halves: kh=1 waves -> LDS -> kh=0 waves add + epilogue
  if (kh == 1) {
#pragma unroll
    for (int m_ = 0; m_ < 3; ++m_)
#pragma unroll
      for (int t_ = 0; t_ < 4; ++t_) comb[p][lane][m_ * 4 + t_] = acc[m_][t_];
  }
  __syncthreads();
  if (kh == 1) return;
#pragma unroll
  for (int m_ = 0; m_ < 3; ++m_)
#pragma unroll
    for (int t_ = 0; t_ < 4; ++t_) {
      const f32x4 o = comb[p][lane][m_ * 4 + t_];
#pragma unroll
      for (int r = 0; r < 4; ++r) acc[m_][t_][r] += o[r];
    }

  const float* bias_p[3] = {bq, bk, bv};
#pragma unroll
  for (int mat = 0; mat < 3; ++mat)
#pragma unroll
    for (int tile = 0; tile < 4; ++tile) {
      const int d = tile * 16 + n;
      const float bias = bias_p[mat][d];
      const int r0 = row0 + quad * 4;   // C-layout: row=quad*4+r, col=n
      f32x4 a = acc[mat][tile];
      if (mat == 0) {
#pragma unroll
        for (int r = 0; r < 4; ++r)
          qs[(size_t)(r0 + r) * DDIM + d] = (f16)((a[r] + bias) * QSCALE);
      } else if (mat == 1) {
#pragma unroll
        for (int r = 0; r < 4; ++r)
          ks[(size_t)(r0 + r) * DDIM + d] = (f16)(a[r] + bias);
      } else {
        const int bb = r0 >> 12;
        const int t = r0 & (SEQ - 1);
        *(f16x4*)(vT + (size_t)(bb * 64 + d) * SEQ + t) =
            cvt4(a[0] + bias, a[1] + bias, a[2] + bias, a[3] + bias);
      }
    }
}

// ---------------- flash attention: transposed softmax, P stays in registers ----
// S' = K·Q^T (C-layout row=key, col=q). PV uses mfma_16x16x16: its B-fragment
// layout [k=quad*4+j][n] IS the S' C-layout -> no LDS round-trip for P.
template <int NSPLIT>
__global__ __launch_bounds__(256, 4) void attn_kernel(const f16* __restrict__ qs,
                                                      const f16* __restrict__ ks,
                                                      const f16* __restrict__ vT,
                                                      float* __restrict__ outp,
                                                      f16* __restrict__ pacc,
                                                      float* __restrict__ pm,
                                                      float* __restrict__ pl) {
  __shared__ __attribute__((aligned(16))) f16 lk[64][SPA];  // [key][d]
  __shared__ __attribute__((aligned(16))) f16 lv[64][SPA];  // [d][key]
  const int tid = threadIdx.x, lane = tid & 63, w = tid >> 6;
  const int n = lane & 15, quad = lane >> 4;
  const int split = blockIdx.x % NSPLIT;
  const int rowblk = blockIdx.x / NSPLIT;
  const int row0 = rowblk * 128 + w * 32;
  const int bb = row0 >> 12;
  const int kbase = split * (SEQ / NSPLIT);
  const int NC = SEQ / NSPLIT / 64;

  const f16* kb = ks + (size_t)bb * SEQ * DDIM;
  const f16* vb = vT + (size_t)bb * DDIM * SEQ;

  const int srow = tid >> 2;          // 0..63
  const int scol = (tid & 3) * 16;    // 0,16,32,48
  const f16* kgp = kb + (size_t)(kbase + srow) * DDIM + scol;
  const f16* vgp = vb + (size_t)srow * SEQ + kbase + scol;

  // persistent Q B-fragments (16x16x32): B[k=d=quad*8+j][col=q=n]
  f16x8 qf[2][2];
#pragma unroll
  for (int g = 0; g < 2; ++g)
#pragma unroll
    for (int hh = 0; hh < 2; ++hh)
      qf[g][hh] = *(const f16x8*)(qs + (size_t)(row0 + g * 16 + n) * DDIM + hh * 32 + quad * 8);

  f32x4 acc[2][4];
  float m[2] = {-1e30f, -1e30f}, ll[2] = {0.f, 0.f};
#pragma unroll
  for (int g = 0; g < 2; ++g)
#pragma unroll
    for (int t = 0; t < 4; ++t) acc[g][t] = (f32x4){0.f, 0.f, 0.f, 0.f};

  f16x8 kr0, kr1, vr0, vr1;
  auto gload = [&](int c) {
    const f16* kp = kgp + (size_t)c * 64 * DDIM;
    kr0 = *(const f16x8*)kp;
    kr1 = *(const f16x8*)(kp + 8);
    const f16* vp = vgp + c * 64;
    vr0 = *(const f16x8*)vp;
    vr1 = *(const f16x8*)(vp + 8);
  };

  gload(0);
  for (int c = 0; c < NC; ++c) {
    *(f16x8*)&lk[srow][scol] = kr0;
    *(f16x8*)&lk[srow][scol + 8] = kr1;
    *(f16x8*)&lv[srow][scol] = vr0;
    *(f16x8*)&lv[srow][scol + 8] = vr1;
    __syncthreads();
    if (c + 1 < NC) gload(c + 1);  // prefetch; drained by end-of-chunk barrier

    // S' = K·Q^T
    f32x4 s[2][4];
#pragma unroll
    for (int st = 0; st < 4; ++st) {
      const f16x8 klo = *(const f16x8*)&lk[st * 16 + n][quad * 8];
      const f16x8 khi = *(const f16x8*)&lk[st * 16 + n][32 + quad * 8];
#pragma unroll
      for (int g = 0; g < 2; ++g) {
        f32x4 z = (f32x4){0.f, 0.f, 0.f, 0.f};
        z = MFMA32(klo, qf[g][0], z);
        s[g][st] = MFMA32(khi, qf[g][1], z);
      }
    }

    // per-lane online softmax; P packed directly as 16x16x16 B-fragments
    f16x4 pq[2][4];
#pragma unroll
    for (int g = 0; g < 2; ++g) {
      f32x4 mx;
#pragma unroll
      for (int r = 0; r < 4; ++r)
        mx[r] = fmaxf(fmaxf(s[g][0][r], s[g][1][r]), fmaxf(s[g][2][r], s[g][3][r]));
      float mloc = fmaxf(fmaxf(mx[0], mx[1]), fmaxf(mx[2], mx[3]));
      mloc = fmaxf(mloc, __shfl_xor(mloc, 16));
      mloc = fmaxf(mloc, __shfl_xor(mloc, 32));
      const float mnew = fmaxf(m[g], mloc);
      const float alpha = __builtin_amdgcn_exp2f(m[g] - mnew);
      m[g] = mnew;
      float psum = 0.f;
#pragma unroll
      for (int st = 0; st < 4; ++st) {
        f32x4 p;
#pragma unroll
        for (int r = 0; r < 4; ++r) p[r] = __builtin_amdgcn_exp2f(s[g][st][r] - mnew);
        psum += (p[0] + p[1]) + (p[2] + p[3]);
        pq[g][st] = cvt4(p[0], p[1], p[2], p[3]);
      }
      ll[g] = ll[g] * alpha + psum;
#pragma unroll
      for (int t = 0; t < 4; ++t) acc[g][t] *= alpha;
    }

    // O^T += V^T·P^T : A = V^T frag [m=d][k=key quad*4+j], B = pq (in-register)
#pragma unroll
    for (int t = 0; t < 4; ++t)
#pragma unroll
      for (int st = 0; st < 4; ++st) {
        const f16x4 va = *(const f16x4*)&lv[t * 16 + n][st * 16 + quad * 4];
        acc[0][t] = MFMA16(va, pq[0][st], acc[0][t]);
        acc[1][t] = MFMA16(va, pq[1][st], acc[1][t]);
      }
    __syncthreads();
  }

  float lred[2];
#pragma unroll
  for (int g = 0; g < 2; ++g) {
    float l = ll[g];
    l += __shfl_xor(l, 16);
    l += __shfl_xor(l, 32);
    lred[g] = l;
  }

  if (NSPLIT == 1) {
#pragma unroll
    for (int g = 0; g < 2; ++g) {
      const float inv = 1.0f / lred[g];
      const int q = row0 + g * 16 + n;
#pragma unroll
      for (int t = 0; t < 4; ++t) {
        f32x4 o = acc[g][t];
#pragma unroll
        for (int r = 0; r < 4; ++r) o[r] *= inv;
        *(f32x4*)(outp + (size_t)q * DDIM + t * 16 + quad * 4) = o;
      }
    }
  } else {
#pragma unroll
    for (int g = 0; g < 2; ++g) {
      const int q = row0 + g * 16 + n;
#pragma unroll
      for (int t = 0; t < 4; ++t)
        *(f16x4*)(pacc + ((size_t)split * NROW + q) * DDIM + t * 16 + quad * 4) =
            cvt4(acc[g][t][0], acc[g][t][1], acc[g][t][2], acc[g][t][3]);
      if (quad == 0) {
        pm[split * NROW + q] = m[g];
        pl[split * NROW + q] = lred[g];
      }
    }
  }
}

// ---------------- split-K combine (f16 partials) ----------------
template <int NSPLIT>
__global__ __launch_bounds__(256) void combine_kernel(const f16* __restrict__ pacc,
                                                      const float* __restrict__ pm,
                                                      const float* __restrict__ pl,
                                                      float* __restrict__ out) {
  const int idx = blockIdx.x * 256 + threadIdx.x;  // NROW*16 units
  const int row = idx >> 4;
  const int c = (idx & 15) * 4;
  float mm = pm[row];
#pragma unroll
  for (int s = 1; s < NSPLIT; ++s) mm = fmaxf(mm, pm[s * NROW + row]);
  float L = 0.f;
  f32x4 o = (f32x4){0.f, 0.f, 0.f, 0.f};
#pragma unroll
  for (int s = 0; s < NSPLIT; ++s) {
    const float e = __builtin_amdgcn_exp2f(pm[s * NROW + row] - mm);
    L += pl[s * NROW + row] * e;
    const f16x4 a = *(const f16x4*)(pacc + ((size_t)s * NROW + row) * DDIM + c);
#pragma unroll
    for (int j = 0; j < 4; ++j) o[j] += (float)a[j] * e;
  }
  const float inv = 1.0f / L;
#pragma unroll
  for (int j = 0; j < 4; ++j) o[j] *= inv;
  *(f32x4*)(out + (size_t)row * DDIM + c) = o;
}

extern "C" void kernel_launch(void* const* d_in, const int* in_sizes, int n_in,
                              void* d_out, int out_size, void* d_ws, size_t ws_size,
                              hipStream_t stream) {
  const float* x  = (const float*)d_in[0];
  const float* Wq = (const float*)d_in[1];
  const float* bq = (const float*)d_in[2];
  const float* Wk = (const float*)d_in[3];
  const float* bk = (const float*)d_in[4];
  const float* Wv = (const float*)d_in[5];
  const float* bv = (const float*)d_in[6];
  float* out = (float*)d_out;

  f16* wf = (f16*)d_ws;                       // 3*64*1024 f16
  f16* qs = wf + 3 * 65536;
  f16* ks = qs + (size_t)NROW * DDIM;
  f16* vT = ks + (size_t)NROW * DDIM;
  f16* pacc = vT + (size_t)NROW * DDIM;       // [NSPL][NROW][64] f16
  float* pm = (float*)(pacc + (size_t)NSPL * NROW * DDIM);
  float* pl = pm + (size_t)NSPL * NROW;
  const size_t need = (size_t)((char*)(pl + (size_t)NSPL * NROW) - (char*)d_ws);

  prep_w_kernel<<<dim3(64), dim3(256), 0, stream>>>(Wq, Wk, Wv, wf);
  proj_kernel<<<dim3(512), dim3(256), 0, stream>>>(x, wf, bq, bk, bv, qs, ks, vT);

  if (ws_size >= need) {
    attn_kernel<NSPL><<<dim3(128 * NSPL), dim3(256), 0, stream>>>(qs, ks, vT, nullptr, pacc, pm, pl);
    combine_kernel<NSPL><<<dim3(NROW * 16 / 256), dim3(256), 0, stream>>>(pacc, pm, pl, out);
  } else {
    attn_kernel<1><<<dim3(128), dim3(256), 0, stream>>>(qs, ks, vT, out, nullptr, nullptr, nullptr);
  }
}

// Round 8
// 170.461 us; speedup vs baseline: 1.1341x; 1.1341x over previous
//
#include <hip/hip_runtime.h>

#define BATCH 4
#define SEQ   4096
#define CDIM  1024
#define DDIM  64
#define NROW  (BATCH * SEQ)   // 16384
#define SPA   70              // attn LDS stride (f16)
#define NSPL  8

typedef _Float16 f16;
typedef _Float16 f16x8 __attribute__((ext_vector_type(8)));
typedef _Float16 f16x4 __attribute__((ext_vector_type(4)));
typedef __fp16   h16x2 __attribute__((ext_vector_type(2)));  // cvt_pkrtz return type
typedef float    f32x4 __attribute__((ext_vector_type(4)));

#define MFMA32(a, b, c) __builtin_amdgcn_mfma_f32_16x16x32_f16((a), (b), (c), 0, 0, 0)
#define MFMA16(a, b, c) __builtin_amdgcn_mfma_f32_16x16x16f16((a), (b), (c), 0, 0, 0)

// async global->LDS DMA, 16 B per lane; LDS dest = uniform base + lane*16
#define GLDS(g, l)                                                            \
  __builtin_amdgcn_global_load_lds((const __attribute__((address_space(1))) void*)(g), \
                                   (__attribute__((address_space(3))) void*)(l), 16, 0, 0)

// scores = (q·k)*8 (the /scale bug); softmax in exp2 domain => fold 8*log2(e) into q
#define QSCALE 11.5415603f

__device__ inline f16x8 cvt8(f32x4 a, f32x4 b) {
  h16x2 p0 = __builtin_amdgcn_cvt_pkrtz(a[0], a[1]);
  h16x2 p1 = __builtin_amdgcn_cvt_pkrtz(a[2], a[3]);
  h16x2 p2 = __builtin_amdgcn_cvt_pkrtz(b[0], b[1]);
  h16x2 p3 = __builtin_amdgcn_cvt_pkrtz(b[2], b[3]);
  f16x8 r;
  r[0] = p0[0]; r[1] = p0[1]; r[2] = p1[0]; r[3] = p1[1];
  r[4] = p2[0]; r[5] = p2[1]; r[6] = p3[0]; r[7] = p3[1];
  return r;
}

__device__ inline f16x4 cvt4(float a, float b, float c, float d) {
  h16x2 lo = __builtin_amdgcn_cvt_pkrtz(a, b);
  h16x2 hi = __builtin_amdgcn_cvt_pkrtz(c, d);
  f16x4 r;
  r[0] = lo[0]; r[1] = lo[1]; r[2] = hi[0]; r[3] = hi[1];
  return r;
}

// ---------------- W fp32 -> f16 prep (once; proj DMAs f16 from L2) ------------
__global__ __launch_bounds__(256) void prep_w_kernel(const float* __restrict__ Wq,
                                                     const float* __restrict__ Wk,
                                                     const float* __restrict__ Wv,
                                                     f16* __restrict__ wf) {
  const int i = (blockIdx.x * 256 + threadIdx.x) * 4;  // 64 blocks cover 65536
  f32x4 a = *(const f32x4*)(Wq + i);
  f32x4 b = *(const f32x4*)(Wk + i);
  f32x4 c = *(const f32x4*)(Wv + i);
  *(f16x4*)(wf + i)          = cvt4(a[0], a[1], a[2], a[3]);
  *(f16x4*)(wf + 65536 + i)  = cvt4(b[0], b[1], b[2], b[3]);
  *(f16x4*)(wf + 131072 + i) = cvt4(c[0], c[1], c[2], c[3]);
}

// ---------------- fused QKV projection: async-DMA double-buffered GEMM --------
// 256 blocks x 4 waves; wave owns 16 rows, full K=1024 in 16 chunks of 64 ch.
// Both x (fp32) and W (f16) staged via global_load_lds; LDS layout is the DMA's
// lane-contiguous order, so all ds_read_b128 are uniform+lane*16 (conflict-free).
// One barrier per chunk; its vmcnt(0) drain paces the HBM stream (m97 pattern).
__global__ __launch_bounds__(256, 1) void proj_kernel(const float* __restrict__ x,
                                                      const f16* __restrict__ wf,
                                                      const float* __restrict__ bq,
                                                      const float* __restrict__ bk,
                                                      const float* __restrict__ bv,
                                                      f16* __restrict__ qs,
                                                      f16* __restrict__ ks,
                                                      f16* __restrict__ vT) {
  __shared__ __attribute__((aligned(16))) float xb[2][4096];   // 2 x 16 KB
  __shared__ __attribute__((aligned(16))) f16 wb[2][12288];    // 2 x 24 KB
  const int tid = threadIdx.x, lane = tid & 63, w = tid >> 6;
  const int n = lane & 15, quad = lane >> 4;
  const int rowbase = blockIdx.x * 64;
  const int row0w = rowbase + w * 16;   // this wave's rows

  // per-thread DMA source pointers (advance by 64 elements per chunk)
  // x instr i (i = c2*2 + h): slot e2 = w*4+i holds x[row0w+n][c2*32+q*8+h*4 ..4]
  const float* xsrc[4];
#pragma unroll
  for (int i = 0; i < 4; ++i) {
    const int c2 = i >> 1, h = i & 1;
    xsrc[i] = x + (size_t)(row0w + n) * CDIM + c2 * 32 + quad * 8 + h * 4;
  }
  // W instr i: e = w*6+i -> (c2e = e/12, mt = e%12); row = (mt>>2)*64+(mt&3)*16+n
  const f16* wsrc[6];
#pragma unroll
  for (int i = 0; i < 6; ++i) {
    const int e = w * 6 + i;
    const int c2e = e / 12, mt = e % 12;
    wsrc[i] = wf + (size_t)((mt >> 2) * 64 + (mt & 3) * 16 + n) * CDIM + c2e * 32 + quad * 8;
  }

  f32x4 acc[12];
#pragma unroll
  for (int t_ = 0; t_ < 12; ++t_) acc[t_] = (f32x4){0.f, 0.f, 0.f, 0.f};

  auto issue = [&](int ck, int b) {
#pragma unroll
    for (int i = 0; i < 4; ++i)
      GLDS(xsrc[i] + ck * 64, &xb[b][(w * 4 + i) * 256]);
#pragma unroll
    for (int i = 0; i < 6; ++i)
      GLDS(wsrc[i] + ck * 64, &wb[b][(w * 6 + i) * 512]);
  };

  issue(0, 0);
  __syncthreads();
  for (int ck = 0; ck < 16; ++ck) {
    const int b = ck & 1;
    if (ck + 1 < 16) issue(ck + 1, b ^ 1);
#pragma unroll
    for (int c2 = 0; c2 < 2; ++c2) {
      const f32x4 x0 = *(const f32x4*)&xb[b][(w * 4 + c2 * 2) * 256 + lane * 4];
      const f32x4 x1 = *(const f32x4*)&xb[b][(w * 4 + c2 * 2 + 1) * 256 + lane * 4];
      const f16x8 a = cvt8(x0, x1);
#pragma unroll
      for (int mt = 0; mt < 12; ++mt) {
        const f16x8 bf = *(const f16x8*)&wb[b][(c2 * 12 + mt) * 512 + lane * 8];
        acc[mt] = MFMA32(a, bf, acc[mt]);
      }
    }
    __syncthreads();  // drains next chunk's DMA; orders LDS reuse
  }

  const float* bias_p[3] = {bq, bk, bv};
#pragma unroll
  for (int mat = 0; mat < 3; ++mat)
#pragma unroll
    for (int tile = 0; tile < 4; ++tile) {
      const int d = tile * 16 + n;
      const float bias = bias_p[mat][d];
      const int r0 = row0w + quad * 4;   // C-layout: row=quad*4+r, col=n
      f32x4 a = acc[mat * 4 + tile];
      if (mat == 0) {
#pragma unroll
        for (int r = 0; r < 4; ++r)
          qs[(size_t)(r0 + r) * DDIM + d] = (f16)((a[r] + bias) * QSCALE);
      } else if (mat == 1) {
#pragma unroll
        for (int r = 0; r < 4; ++r)
          ks[(size_t)(r0 + r) * DDIM + d] = (f16)(a[r] + bias);
      } else {
        const int bb = r0 >> 12;
        const int t = r0 & (SEQ - 1);
        *(f16x4*)(vT + (size_t)(bb * 64 + d) * SEQ + t) =
            cvt4(a[0] + bias, a[1] + bias, a[2] + bias, a[3] + bias);
      }
    }
}

// ---------------- flash attention: transposed softmax, P stays in registers ----
// S' = K·Q^T (C-layout row=key, col=q). PV uses mfma_16x16x16: its B-fragment
// layout [k=quad*4+j][n] IS the S' C-layout -> no LDS round-trip for P.
template <int NSPLIT>
__global__ __launch_bounds__(256, 4) void attn_kernel(const f16* __restrict__ qs,
                                                      const f16* __restrict__ ks,
                                                      const f16* __restrict__ vT,
                                                      float* __restrict__ outp,
                                                      f16* __restrict__ pacc,
                                                      float* __restrict__ pm,
                                                      float* __restrict__ pl) {
  __shared__ __attribute__((aligned(16))) f16 lk[64][SPA];  // [key][d]
  __shared__ __attribute__((aligned(16))) f16 lv[64][SPA];  // [d][key]
  const int tid = threadIdx.x, lane = tid & 63, w = tid >> 6;
  const int n = lane & 15, quad = lane >> 4;
  const int split = blockIdx.x % NSPLIT;
  const int rowblk = blockIdx.x / NSPLIT;
  const int row0 = rowblk * 128 + w * 32;
  const int bb = row0 >> 12;
  const int kbase = split * (SEQ / NSPLIT);
  const int NC = SEQ / NSPLIT / 64;

  const f16* kb = ks + (size_t)bb * SEQ * DDIM;
  const f16* vb = vT + (size_t)bb * DDIM * SEQ;

  const int srow = tid >> 2;          // 0..63
  const int scol = (tid & 3) * 16;    // 0,16,32,48
  const f16* kgp = kb + (size_t)(kbase + srow) * DDIM + scol;
  const f16* vgp = vb + (size_t)srow * SEQ + kbase + scol;

  // persistent Q B-fragments (16x16x32): B[k=d=quad*8+j][col=q=n]
  f16x8 qf[2][2];
#pragma unroll
  for (int g = 0; g < 2; ++g)
#pragma unroll
    for (int hh = 0; hh < 2; ++hh)
      qf[g][hh] = *(const f16x8*)(qs + (size_t)(row0 + g * 16 + n) * DDIM + hh * 32 + quad * 8);

  f32x4 acc[2][4];
  float m[2] = {-1e30f, -1e30f}, ll[2] = {0.f, 0.f};
#pragma unroll
  for (int g = 0; g < 2; ++g)
#pragma unroll
    for (int t = 0; t < 4; ++t) acc[g][t] = (f32x4){0.f, 0.f, 0.f, 0.f};

  f16x8 kr0, kr1, vr0, vr1;
  auto gload = [&](int c) {
    const f16* kp = kgp + (size_t)c * 64 * DDIM;
    kr0 = *(const f16x8*)kp;
    kr1 = *(const f16x8*)(kp + 8);
    const f16* vp = vgp + c * 64;
    vr0 = *(const f16x8*)vp;
    vr1 = *(const f16x8*)(vp + 8);
  };

  gload(0);
  for (int c = 0; c < NC; ++c) {
    *(f16x8*)&lk[srow][scol] = kr0;
    *(f16x8*)&lk[srow][scol + 8] = kr1;
    *(f16x8*)&lv[srow][scol] = vr0;
    *(f16x8*)&lv[srow][scol + 8] = vr1;
    __syncthreads();
    if (c + 1 < NC) gload(c + 1);  // prefetch; drained by end-of-chunk barrier

    // S' = K·Q^T
    f32x4 s[2][4];
#pragma unroll
    for (int st = 0; st < 4; ++st) {
      const f16x8 klo = *(const f16x8*)&lk[st * 16 + n][quad * 8];
      const f16x8 khi = *(const f16x8*)&lk[st * 16 + n][32 + quad * 8];
#pragma unroll
      for (int g = 0; g < 2; ++g) {
        f32x4 z = (f32x4){0.f, 0.f, 0.f, 0.f};
        z = MFMA32(klo, qf[g][0], z);
        s[g][st] = MFMA32(khi, qf[g][1], z);
      }
    }

    // per-lane online softmax; P packed directly as 16x16x16 B-fragments
    f16x4 pq[2][4];
#pragma unroll
    for (int g = 0; g < 2; ++g) {
      f32x4 mx;
#pragma unroll
      for (int r = 0; r < 4; ++r)
        mx[r] = fmaxf(fmaxf(s[g][0][r], s[g][1][r]), fmaxf(s[g][2][r], s[g][3][r]));
      float mloc = fmaxf(fmaxf(mx[0], mx[1]), fmaxf(mx[2], mx[3]));
      mloc = fmaxf(mloc, __shfl_xor(mloc, 16));
      mloc = fmaxf(mloc, __shfl_xor(mloc, 32));
      const float mnew = fmaxf(m[g], mloc);
      const float alpha = __builtin_amdgcn_exp2f(m[g] - mnew);
      m[g] = mnew;
      float psum = 0.f;
#pragma unroll
      for (int st = 0; st < 4; ++st) {
        f32x4 p;
#pragma unroll
        for (int r = 0; r < 4; ++r) p[r] = __builtin_amdgcn_exp2f(s[g][st][r] - mnew);
        psum += (p[0] + p[1]) + (p[2] + p[3]);
        pq[g][st] = cvt4(p[0], p[1], p[2], p[3]);
      }
      ll[g] = ll[g] * alpha + psum;
#pragma unroll
      for (int t = 0; t < 4; ++t) acc[g][t] *= alpha;
    }

    // O^T += V^T·P^T : A = V^T frag [m=d][k=key quad*4+j], B = pq (in-register)
#pragma unroll
    for (int t = 0; t < 4; ++t)
#pragma unroll
      for (int st = 0; st < 4; ++st) {
        const f16x4 va = *(const f16x4*)&lv[t * 16 + n][st * 16 + quad * 4];
        acc[0][t] = MFMA16(va, pq[0][st], acc[0][t]);
        acc[1][t] = MFMA16(va, pq[1][st], acc[1][t]);
      }
    __syncthreads();
  }

  float lred[2];
#pragma unroll
  for (int g = 0; g < 2; ++g) {
    float l = ll[g];
    l += __shfl_xor(l, 16);
    l += __shfl_xor(l, 32);
    lred[g] = l;
  }

  if (NSPLIT == 1) {
#pragma unroll
    for (int g = 0; g < 2; ++g) {
      const float inv = 1.0f / lred[g];
      const int q = row0 + g * 16 + n;
#pragma unroll
      for (int t = 0; t < 4; ++t) {
        f32x4 o = acc[g][t];
#pragma unroll
        for (int r = 0; r < 4; ++r) o[r] *= inv;
        *(f32x4*)(outp + (size_t)q * DDIM + t * 16 + quad * 4) = o;
      }
    }
  } else {
#pragma unroll
    for (int g = 0; g < 2; ++g) {
      const int q = row0 + g * 16 + n;
#pragma unroll
      for (int t = 0; t < 4; ++t)
        *(f16x4*)(pacc + ((size_t)split * NROW + q) * DDIM + t * 16 + quad * 4) =
            cvt4(acc[g][t][0], acc[g][t][1], acc[g][t][2], acc[g][t][3]);
      if (quad == 0) {
        pm[split * NROW + q] = m[g];
        pl[split * NROW + q] = lred[g];
      }
    }
  }
}

// ---------------- split-K combine (f16 partials) ----------------
template <int NSPLIT>
__global__ __launch_bounds__(256) void combine_kernel(const f16* __restrict__ pacc,
                                                      const float* __restrict__ pm,
                                                      const float* __restrict__ pl,
                                                      float* __restrict__ out) {
  const int idx = blockIdx.x * 256 + threadIdx.x;  // NROW*16 units
  const int row = idx >> 4;
  const int c = (idx & 15) * 4;
  float mm = pm[row];
#pragma unroll
  for (int s = 1; s < NSPLIT; ++s) mm = fmaxf(mm, pm[s * NROW + row]);
  float L = 0.f;
  f32x4 o = (f32x4){0.f, 0.f, 0.f, 0.f};
#pragma unroll
  for (int s = 0; s < NSPLIT; ++s) {
    const float e = __builtin_amdgcn_exp2f(pm[s * NROW + row] - mm);
    L += pl[s * NROW + row] * e;
    const f16x4 a = *(const f16x4*)(pacc + ((size_t)s * NROW + row) * DDIM + c);
#pragma unroll
    for (int j = 0; j < 4; ++j) o[j] += (float)a[j] * e;
  }
  const float inv = 1.0f / L;
#pragma unroll
  for (int j = 0; j < 4; ++j) o[j] *= inv;
  *(f32x4*)(out + (size_t)row * DDIM + c) = o;
}

extern "C" void kernel_launch(void* const* d_in, const int* in_sizes, int n_in,
                              void* d_out, int out_size, void* d_ws, size_t ws_size,
                              hipStream_t stream) {
  const float* x  = (const float*)d_in[0];
  const float* Wq = (const float*)d_in[1];
  const float* bq = (const float*)d_in[2];
  const float* Wk = (const float*)d_in[3];
  const float* bk = (const float*)d_in[4];
  const float* Wv = (const float*)d_in[5];
  const float* bv = (const float*)d_in[6];
  float* out = (float*)d_out;

  f16* wf = (f16*)d_ws;                       // 3*64*1024 f16
  f16* qs = wf + 3 * 65536;
  f16* ks = qs + (size_t)NROW * DDIM;
  f16* vT = ks + (size_t)NROW * DDIM;
  f16* pacc = vT + (size_t)NROW * DDIM;       // [NSPL][NROW][64] f16
  float* pm = (float*)(pacc + (size_t)NSPL * NROW * DDIM);
  float* pl = pm + (size_t)NSPL * NROW;
  const size_t need = (size_t)((char*)(pl + (size_t)NSPL * NROW) - (char*)d_ws);

  prep_w_kernel<<<dim3(64), dim3(256), 0, stream>>>(Wq, Wk, Wv, wf);
  proj_kernel<<<dim3(256), dim3(256), 0, stream>>>(x, wf, bq, bk, bv, qs, ks, vT);

  if (ws_size >= need) {
    attn_kernel<NSPL><<<dim3(128 * NSPL), dim3(256), 0, stream>>>(qs, ks, vT, nullptr, pacc, pm, pl);
    combine_kernel<NSPL><<<dim3(NROW * 16 / 256), dim3(256), 0, stream>>>(pacc, pm, pl, out);
  } else {
    attn_kernel<1><<<dim3(128), dim3(256), 0, stream>>>(qs, ks, vT, out, nullptr, nullptr, nullptr);
  }
}

// Round 9
// 170.086 us; speedup vs baseline: 1.1366x; 1.0022x over previous
//
#include <hip/hip_runtime.h>

#define BATCH 4
#define SEQ   4096
#define CDIM  1024
#define DDIM  64
#define NROW  (BATCH * SEQ)   // 16384
#define SPA   70              // attn LDS stride (f16)
#define NSPL  8

typedef _Float16 f16;
typedef _Float16 f16x8 __attribute__((ext_vector_type(8)));
typedef _Float16 f16x4 __attribute__((ext_vector_type(4)));
typedef __fp16   h16x2 __attribute__((ext_vector_type(2)));  // cvt_pkrtz return type
typedef float    f32x4 __attribute__((ext_vector_type(4)));

#define MFMA32(a, b, c) __builtin_amdgcn_mfma_f32_16x16x32_f16((a), (b), (c), 0, 0, 0)
#define MFMA16(a, b, c) __builtin_amdgcn_mfma_f32_16x16x16f16((a), (b), (c), 0, 0, 0)

// async global->LDS DMA, 16 B per lane; LDS dest = uniform base + lane*16
#define GLDS(g, l)                                                            \
  __builtin_amdgcn_global_load_lds((const __attribute__((address_space(1))) void*)(g), \
                                   (__attribute__((address_space(3))) void*)(l), 16, 0, 0)

// scores = (q·k)*8 (the /scale bug); softmax in exp2 domain => fold 8*log2(e) into q
#define QSCALE 11.5415603f

__device__ inline f16x8 cvt8(f32x4 a, f32x4 b) {
  h16x2 p0 = __builtin_amdgcn_cvt_pkrtz(a[0], a[1]);
  h16x2 p1 = __builtin_amdgcn_cvt_pkrtz(a[2], a[3]);
  h16x2 p2 = __builtin_amdgcn_cvt_pkrtz(b[0], b[1]);
  h16x2 p3 = __builtin_amdgcn_cvt_pkrtz(b[2], b[3]);
  f16x8 r;
  r[0] = p0[0]; r[1] = p0[1]; r[2] = p1[0]; r[3] = p1[1];
  r[4] = p2[0]; r[5] = p2[1]; r[6] = p3[0]; r[7] = p3[1];
  return r;
}

__device__ inline f16x4 cvt4(float a, float b, float c, float d) {
  h16x2 lo = __builtin_amdgcn_cvt_pkrtz(a, b);
  h16x2 hi = __builtin_amdgcn_cvt_pkrtz(c, d);
  f16x4 r;
  r[0] = lo[0]; r[1] = lo[1]; r[2] = hi[0]; r[3] = hi[1];
  return r;
}

// ---------------- W fp32 -> f16 prep (once; proj DMAs f16 from L2) ------------
__global__ __launch_bounds__(256) void prep_w_kernel(const float* __restrict__ Wq,
                                                     const float* __restrict__ Wk,
                                                     const float* __restrict__ Wv,
                                                     f16* __restrict__ wf) {
  const int i = (blockIdx.x * 256 + threadIdx.x) * 4;  // 64 blocks cover 65536
  f32x4 a = *(const f32x4*)(Wq + i);
  f32x4 b = *(const f32x4*)(Wk + i);
  f32x4 c = *(const f32x4*)(Wv + i);
  *(f16x4*)(wf + i)          = cvt4(a[0], a[1], a[2], a[3]);
  *(f16x4*)(wf + 65536 + i)  = cvt4(b[0], b[1], b[2], b[3]);
  *(f16x4*)(wf + 131072 + i) = cvt4(c[0], c[1], c[2], c[3]);
}

// ---------------- fused QKV projection: 2 blocks/CU DMA pipeline --------------
// 512 blocks x 4 waves, 32 rows/block. Wave (rw = w&1, kh = w>>1): rows
// [blk*32 + rw*16, +16), channels [kh*512, +512) in 16 chunks of 32.
// x + W staged via global_load_lds in DMA lane order (conflict-free b128 reads).
// LDS = 64 KB/block -> 2 blocks/CU: one block's compute covers the other's
// barrier drain. K halves combined through LDS at the end.
__global__ __launch_bounds__(256, 2) void proj_kernel(const float* __restrict__ x,
                                                      const f16* __restrict__ wf,
                                                      const float* __restrict__ bq,
                                                      const float* __restrict__ bk,
                                                      const float* __restrict__ bv,
                                                      f16* __restrict__ qs,
                                                      f16* __restrict__ ks,
                                                      f16* __restrict__ vT) {
  __shared__ __attribute__((aligned(16))) char smem[65536];
  float(*xb)[4][512] = (float(*)[4][512])smem;             // [buf][w][2x256] 16 KB
  f16(*wb)[2][12][512] = (f16(*)[2][12][512])(smem + 16384);  // [buf][kh][mt][512] 48 KB
  f32x4(*comb)[64][12] = (f32x4(*)[64][12])smem;           // end-of-kernel reuse, 24 KB

  const int tid = threadIdx.x, lane = tid & 63, w = tid >> 6;
  const int n = lane & 15, quad = lane >> 4;
  const int rw = w & 1;    // row half
  const int kh = w >> 1;   // channel (K) half
  const int row0w = blockIdx.x * 32 + rw * 16;

  // DMA sources (advance 32 elements/chunk)
  const float* xsrc[2];
#pragma unroll
  for (int h = 0; h < 2; ++h)
    xsrc[h] = x + (size_t)(row0w + n) * CDIM + kh * 512 + quad * 8 + h * 4;
  const f16* wsrc[6];
#pragma unroll
  for (int i = 0; i < 6; ++i) {
    const int mt = rw * 6 + i;  // this wave stages 6 of its kh's 12 W slots
    wsrc[i] = wf + (size_t)((mt >> 2) * 64 + (mt & 3) * 16 + n) * CDIM + kh * 512 + quad * 8;
  }

  f32x4 acc[12];
#pragma unroll
  for (int t_ = 0; t_ < 12; ++t_) acc[t_] = (f32x4){0.f, 0.f, 0.f, 0.f};

  auto issue = [&](int ck, int b) {
#pragma unroll
    for (int h = 0; h < 2; ++h)
      GLDS(xsrc[h] + ck * 32, &xb[b][w][h * 256]);
#pragma unroll
    for (int i = 0; i < 6; ++i)
      GLDS(wsrc[i] + ck * 32, &wb[b][kh][rw * 6 + i][0]);
  };

  issue(0, 0);
  __syncthreads();
  for (int ck = 0; ck < 16; ++ck) {
    const int b = ck & 1;
    if (ck + 1 < 16) issue(ck + 1, b ^ 1);
    const f32x4 x0 = *(const f32x4*)&xb[b][w][lane * 4];
    const f32x4 x1 = *(const f32x4*)&xb[b][w][256 + lane * 4];
    const f16x8 a = cvt8(x0, x1);
#pragma unroll
    for (int mt = 0; mt < 12; ++mt) {
      const f16x8 bf = *(const f16x8*)&wb[b][kh][mt][lane * 8];
      acc[mt] = MFMA32(a, bf, acc[mt]);
    }
    __syncthreads();  // drains next chunk's DMA; orders LDS reuse
  }

  // combine K halves: kh=1 waves -> LDS -> kh=0 waves add + epilogue
  if (kh == 1) {
#pragma unroll
    for (int t_ = 0; t_ < 12; ++t_) comb[rw][lane][t_] = acc[t_];
  }
  __syncthreads();
  if (kh == 1) return;
#pragma unroll
  for (int t_ = 0; t_ < 12; ++t_) {
    const f32x4 o = comb[rw][lane][t_];
#pragma unroll
    for (int r = 0; r < 4; ++r) acc[t_][r] += o[r];
  }

  const float* bias_p[3] = {bq, bk, bv};
#pragma unroll
  for (int mat = 0; mat < 3; ++mat)
#pragma unroll
    for (int tile = 0; tile < 4; ++tile) {
      const int d = tile * 16 + n;
      const float bias = bias_p[mat][d];
      const int r0 = row0w + quad * 4;   // C-layout: row=quad*4+r, col=n
      f32x4 a = acc[mat * 4 + tile];
      if (mat == 0) {
#pragma unroll
        for (int r = 0; r < 4; ++r)
          qs[(size_t)(r0 + r) * DDIM + d] = (f16)((a[r] + bias) * QSCALE);
      } else if (mat == 1) {
#pragma unroll
        for (int r = 0; r < 4; ++r)
          ks[(size_t)(r0 + r) * DDIM + d] = (f16)(a[r] + bias);
      } else {
        const int bb = r0 >> 12;
        const int t = r0 & (SEQ - 1);
        *(f16x4*)(vT + (size_t)(bb * 64 + d) * SEQ + t) =
            cvt4(a[0] + bias, a[1] + bias, a[2] + bias, a[3] + bias);
      }
    }
}

// ---------------- flash attention: transposed softmax, P stays in registers ----
// S' = K·Q^T (C-layout row=key, col=q). PV uses mfma_16x16x16: its B-fragment
// layout [k=quad*4+j][n] IS the S' C-layout -> no LDS round-trip for P.
template <int NSPLIT>
__global__ __launch_bounds__(256, 4) void attn_kernel(const f16* __restrict__ qs,
                                                      const f16* __restrict__ ks,
                                                      const f16* __restrict__ vT,
                                                      float* __restrict__ outp,
                                                      f16* __restrict__ pacc,
                                                      float* __restrict__ pm,
                                                      float* __restrict__ pl) {
  __shared__ __attribute__((aligned(16))) f16 lk[64][SPA];  // [key][d]
  __shared__ __attribute__((aligned(16))) f16 lv[64][SPA];  // [d][key]
  const int tid = threadIdx.x, lane = tid & 63, w = tid >> 6;
  const int n = lane & 15, quad = lane >> 4;
  const int split = blockIdx.x % NSPLIT;
  const int rowblk = blockIdx.x / NSPLIT;
  const int row0 = rowblk * 128 + w * 32;
  const int bb = row0 >> 12;
  const int kbase = split * (SEQ / NSPLIT);
  const int NC = SEQ / NSPLIT / 64;

  const f16* kb = ks + (size_t)bb * SEQ * DDIM;
  const f16* vb = vT + (size_t)bb * DDIM * SEQ;

  const int srow = tid >> 2;          // 0..63
  const int scol = (tid & 3) * 16;    // 0,16,32,48
  const f16* kgp = kb + (size_t)(kbase + srow) * DDIM + scol;
  const f16* vgp = vb + (size_t)srow * SEQ + kbase + scol;

  // persistent Q B-fragments (16x16x32): B[k=d=quad*8+j][col=q=n]
  f16x8 qf[2][2];
#pragma unroll
  for (int g = 0; g < 2; ++g)
#pragma unroll
    for (int hh = 0; hh < 2; ++hh)
      qf[g][hh] = *(const f16x8*)(qs + (size_t)(row0 + g * 16 + n) * DDIM + hh * 32 + quad * 8);

  f32x4 acc[2][4];
  float m[2] = {-1e30f, -1e30f}, ll[2] = {0.f, 0.f};
#pragma unroll
  for (int g = 0; g < 2; ++g)
#pragma unroll
    for (int t = 0; t < 4; ++t) acc[g][t] = (f32x4){0.f, 0.f, 0.f, 0.f};

  f16x8 kr0, kr1, vr0, vr1;
  auto gload = [&](int c) {
    const f16* kp = kgp + (size_t)c * 64 * DDIM;
    kr0 = *(const f16x8*)kp;
    kr1 = *(const f16x8*)(kp + 8);
    const f16* vp = vgp + c * 64;
    vr0 = *(const f16x8*)vp;
    vr1 = *(const f16x8*)(vp + 8);
  };

  gload(0);
  for (int c = 0; c < NC; ++c) {
    *(f16x8*)&lk[srow][scol] = kr0;
    *(f16x8*)&lk[srow][scol + 8] = kr1;
    *(f16x8*)&lv[srow][scol] = vr0;
    *(f16x8*)&lv[srow][scol + 8] = vr1;
    __syncthreads();
    if (c + 1 < NC) gload(c + 1);  // prefetch; drained by end-of-chunk barrier

    // S' = K·Q^T
    f32x4 s[2][4];
#pragma unroll
    for (int st = 0; st < 4; ++st) {
      const f16x8 klo = *(const f16x8*)&lk[st * 16 + n][quad * 8];
      const f16x8 khi = *(const f16x8*)&lk[st * 16 + n][32 + quad * 8];
#pragma unroll
      for (int g = 0; g < 2; ++g) {
        f32x4 z = (f32x4){0.f, 0.f, 0.f, 0.f};
        z = MFMA32(klo, qf[g][0], z);
        s[g][st] = MFMA32(khi, qf[g][1], z);
      }
    }

    // per-lane online softmax; P packed directly as 16x16x16 B-fragments
    f16x4 pq[2][4];
#pragma unroll
    for (int g = 0; g < 2; ++g) {
      f32x4 mx;
#pragma unroll
      for (int r = 0; r < 4; ++r)
        mx[r] = fmaxf(fmaxf(s[g][0][r], s[g][1][r]), fmaxf(s[g][2][r], s[g][3][r]));
      float mloc = fmaxf(fmaxf(mx[0], mx[1]), fmaxf(mx[2], mx[3]));
      mloc = fmaxf(mloc, __shfl_xor(mloc, 16));
      mloc = fmaxf(mloc, __shfl_xor(mloc, 32));
      const float mnew = fmaxf(m[g], mloc);
      const float alpha = __builtin_amdgcn_exp2f(m[g] - mnew);
      m[g] = mnew;
      float psum = 0.f;
#pragma unroll
      for (int st = 0; st < 4; ++st) {
        f32x4 p;
#pragma unroll
        for (int r = 0; r < 4; ++r) p[r] = __builtin_amdgcn_exp2f(s[g][st][r] - mnew);
        psum += (p[0] + p[1]) + (p[2] + p[3]);
        pq[g][st] = cvt4(p[0], p[1], p[2], p[3]);
      }
      ll[g] = ll[g] * alpha + psum;
#pragma unroll
      for (int t = 0; t < 4; ++t) acc[g][t] *= alpha;
    }

    // O^T += V^T·P^T : A = V^T frag [m=d][k=key quad*4+j], B = pq (in-register)
#pragma unroll
    for (int t = 0; t < 4; ++t)
#pragma unroll
      for (int st = 0; st < 4; ++st) {
        const f16x4 va = *(const f16x4*)&lv[t * 16 + n][st * 16 + quad * 4];
        acc[0][t] = MFMA16(va, pq[0][st], acc[0][t]);
        acc[1][t] = MFMA16(va, pq[1][st], acc[1][t]);
      }
    __syncthreads();
  }

  float lred[2];
#pragma unroll
  for (int g = 0; g < 2; ++g) {
    float l = ll[g];
    l += __shfl_xor(l, 16);
    l += __shfl_xor(l, 32);
    lred[g] = l;
  }

  if (NSPLIT == 1) {
#pragma unroll
    for (int g = 0; g < 2; ++g) {
      const float inv = 1.0f / lred[g];
      const int q = row0 + g * 16 + n;
#pragma unroll
      for (int t = 0; t < 4; ++t) {
        f32x4 o = acc[g][t];
#pragma unroll
        for (int r = 0; r < 4; ++r) o[r] *= inv;
        *(f32x4*)(outp + (size_t)q * DDIM + t * 16 + quad * 4) = o;
      }
    }
  } else {
#pragma unroll
    for (int g = 0; g < 2; ++g) {
      const int q = row0 + g * 16 + n;
#pragma unroll
      for (int t = 0; t < 4; ++t)
        *(f16x4*)(pacc + ((size_t)split * NROW + q) * DDIM + t * 16 + quad * 4) =
            cvt4(acc[g][t][0], acc[g][t][1], acc[g][t][2], acc[g][t][3]);
      if (quad == 0) {
        pm[split * NROW + q] = m[g];
        pl[split * NROW + q] = lred[g];
      }
    }
  }
}

// ---------------- split-K combine (f16 partials) ----------------
template <int NSPLIT>
__global__ __launch_bounds__(256) void combine_kernel(const f16* __restrict__ pacc,
                                                      const float* __restrict__ pm,
                                                      const float* __restrict__ pl,
                                                      float* __restrict__ out) {
  const int idx = blockIdx.x * 256 + threadIdx.x;  // NROW*16 units
  const int row = idx >> 4;
  const int c = (idx & 15) * 4;
  float mm = pm[row];
#pragma unroll
  for (int s = 1; s < NSPLIT; ++s) mm = fmaxf(mm, pm[s * NROW + row]);
  float L = 0.f;
  f32x4 o = (f32x4){0.f, 0.f, 0.f, 0.f};
#pragma unroll
  for (int s = 0; s < NSPLIT; ++s) {
    const float e = __builtin_amdgcn_exp2f(pm[s * NROW + row] - mm);
    L += pl[s * NROW + row] * e;
    const f16x4 a = *(const f16x4*)(pacc + ((size_t)s * NROW + row) * DDIM + c);
#pragma unroll
    for (int j = 0; j < 4; ++j) o[j] += (float)a[j] * e;
  }
  const float inv = 1.0f / L;
#pragma unroll
  for (int j = 0; j < 4; ++j) o[j] *= inv;
  *(f32x4*)(out + (size_t)row * DDIM + c) = o;
}

extern "C" void kernel_launch(void* const* d_in, const int* in_sizes, int n_in,
                              void* d_out, int out_size, void* d_ws, size_t ws_size,
                              hipStream_t stream) {
  const float* x  = (const float*)d_in[0];
  const float* Wq = (const float*)d_in[1];
  const float* bq = (const float*)d_in[2];
  const float* Wk = (const float*)d_in[3];
  const float* bk = (const float*)d_in[4];
  const float* Wv = (const float*)d_in[5];
  const float* bv = (const float*)d_in[6];
  float* out = (float*)d_out;

  f16* wf = (f16*)d_ws;                       // 3*64*1024 f16
  f16* qs = wf + 3 * 65536;
  f16* ks = qs + (size_t)NROW * DDIM;
  f16* vT = ks + (size_t)NROW * DDIM;
  f16* pacc = vT + (size_t)NROW * DDIM;       // [NSPL][NROW][64] f16
  float* pm = (float*)(pacc + (size_t)NSPL * NROW * DDIM);
  float* pl = pm + (size_t)NSPL * NROW;
  const size_t need = (size_t)((char*)(pl + (size_t)NSPL * NROW) - (char*)d_ws);

  prep_w_kernel<<<dim3(64), dim3(256), 0, stream>>>(Wq, Wk, Wv, wf);
  proj_kernel<<<dim3(512), dim3(256), 0, stream>>>(x, wf, bq, bk, bv, qs, ks, vT);

  if (ws_size >= need) {
    attn_kernel<NSPL><<<dim3(128 * NSPL), dim3(256), 0, stream>>>(qs, ks, vT, nullptr, pacc, pm, pl);
    combine_kernel<NSPL><<<dim3(NROW * 16 / 256), dim3(256), 0, stream>>>(pacc, pm, pl, out);
  } else {
    attn_kernel<1><<<dim3(128), dim3(256), 0, stream>>>(qs, ks, vT, out, nullptr, nullptr, nullptr);
  }
}

// Round 10
// 164.668 us; speedup vs baseline: 1.1740x; 1.0329x over previous
//
#include <hip/hip_runtime.h>

#define BATCH 4
#define SEQ   4096
#define CDIM  1024
#define DDIM  64
#define NROW  (BATCH * SEQ)   // 16384
#define SPA   70              // attn LDS stride (f16)
#define NSPL  8

typedef _Float16 f16;
typedef _Float16 f16x8 __attribute__((ext_vector_type(8)));
typedef _Float16 f16x4 __attribute__((ext_vector_type(4)));
typedef __fp16   h16x2 __attribute__((ext_vector_type(2)));  // cvt_pkrtz return type
typedef float    f32x4 __attribute__((ext_vector_type(4)));

#define MFMA32(a, b, c) __builtin_amdgcn_mfma_f32_16x16x32_f16((a), (b), (c), 0, 0, 0)
#define MFMA16(a, b, c) __builtin_amdgcn_mfma_f32_16x16x16f16((a), (b), (c), 0, 0, 0)

// async global->LDS DMA, 16 B per lane; LDS dest = wave-uniform base + lane*16
#define GLDS(g, l)                                                            \
  __builtin_amdgcn_global_load_lds((const __attribute__((address_space(1))) void*)(g), \
                                   (__attribute__((address_space(3))) void*)(l), 16, 0, 0)

// scores = (q·k)*8 (the /scale bug); softmax in exp2 domain => fold 8*log2(e) into q
#define QSCALE 11.5415603f

__device__ inline f16x8 cvt8(f32x4 a, f32x4 b) {
  h16x2 p0 = __builtin_amdgcn_cvt_pkrtz(a[0], a[1]);
  h16x2 p1 = __builtin_amdgcn_cvt_pkrtz(a[2], a[3]);
  h16x2 p2 = __builtin_amdgcn_cvt_pkrtz(b[0], b[1]);
  h16x2 p3 = __builtin_amdgcn_cvt_pkrtz(b[2], b[3]);
  f16x8 r;
  r[0] = p0[0]; r[1] = p0[1]; r[2] = p1[0]; r[3] = p1[1];
  r[4] = p2[0]; r[5] = p2[1]; r[6] = p3[0]; r[7] = p3[1];
  return r;
}

__device__ inline f16x4 cvt4(float a, float b, float c, float d) {
  h16x2 lo = __builtin_amdgcn_cvt_pkrtz(a, b);
  h16x2 hi = __builtin_amdgcn_cvt_pkrtz(c, d);
  f16x4 r;
  r[0] = lo[0]; r[1] = lo[1]; r[2] = hi[0]; r[3] = hi[1];
  return r;
}

// ---------------- W prep: fp32 -> f16, shuffled into per-chunk DMA order ------
// wf2 slot s = ck*12 + mt (ck 0..31 = 32-ch chunk, mt = mat*4+tile), 512 f16:
// wf2[s*512 + (quad*16+n)*8 + e] = W[mat][tile*16+n][ck*32 + quad*8 + e].
// proj's W DMA then reads 1 KB fully contiguous per instruction.
__global__ __launch_bounds__(256) void prep_w_kernel(const float* __restrict__ Wq,
                                                     const float* __restrict__ Wk,
                                                     const float* __restrict__ Wv,
                                                     f16* __restrict__ wf2) {
  const int t = blockIdx.x * 256 + threadIdx.x;  // 96 blocks -> 24576 threads
  const int lane = t & 63;
  const int s = t >> 6;                // 0..383
  const int mt = s % 12, ck = s / 12;
  const int mat = mt >> 2, tile = mt & 3;
  const int n = lane & 15, quad = lane >> 4;
  const float* W = (mat == 0) ? Wq : (mat == 1) ? Wk : Wv;
  const float* src = W + (size_t)(tile * 16 + n) * CDIM + ck * 32 + quad * 8;
  const f32x4 a = *(const f32x4*)src;
  const f32x4 b = *(const f32x4*)(src + 4);
  *(f16x8*)(wf2 + (size_t)t * 8) = cvt8(a, b);
}

// ---------------- fused QKV projection: contiguous-DMA pipeline ---------------
// 512 blocks x 4 waves, 32 rows/block, full K (no split). Wave w computes all
// 32 rows x 48 cols (mt slots w*3..w*3+2). Per 32-ch chunk: wave issues 1 x-DMA
// (8 rows x 128 B contiguous segments) + 3 W-DMAs (1 KB pure bursts from wf2's
// shuffled layout); double-buffered 32 KB LDS -> 2 blocks/CU.
__global__ __launch_bounds__(256, 2) void proj_kernel(const float* __restrict__ x,
                                                      const f16* __restrict__ wf2,
                                                      const float* __restrict__ bq,
                                                      const float* __restrict__ bk,
                                                      const float* __restrict__ bv,
                                                      f16* __restrict__ qs,
                                                      f16* __restrict__ ks,
                                                      f16* __restrict__ vT) {
  __shared__ __attribute__((aligned(16))) char smem[2 * 16384];  // [buf][x 4K | w 12K]
  const int tid = threadIdx.x, lane = tid & 63, w = tid >> 6;
  const int n = lane & 15, quad = lane >> 4;
  const int rowbase = blockIdx.x * 32;

  // per-lane DMA sources
  const float* xsl = x + (size_t)(rowbase + w * 8 + (lane >> 3)) * CDIM + (lane & 7) * 4;
  const f16* wsl[3];
#pragma unroll
  for (int i = 0; i < 3; ++i)
    wsl[i] = wf2 + (size_t)(w * 3 + i) * 512 + lane * 8;

  f32x4 acc[2][3];
#pragma unroll
  for (int g = 0; g < 2; ++g)
#pragma unroll
    for (int i = 0; i < 3; ++i) acc[g][i] = (f32x4){0.f, 0.f, 0.f, 0.f};

  auto issue = [&](int ck, int b) {
    char* base = smem + b * 16384;
    GLDS(xsl + ck * 32, base + w * 1024);
#pragma unroll
    for (int i = 0; i < 3; ++i)
      GLDS(wsl[i] + (size_t)ck * 12 * 512, base + 4096 + (w * 3 + i) * 1024);
  };

  issue(0, 0);
  __syncthreads();
  for (int ck = 0; ck < 32; ++ck) {
    const int b = ck & 1;
    if (ck + 1 < 32) issue(ck + 1, b ^ 1);
    const float* xb = (const float*)(smem + b * 16384);
    const f16* wb = (const f16*)(smem + b * 16384 + 4096);
    f16x8 a[2];
#pragma unroll
    for (int g = 0; g < 2; ++g) {
      const f32x4 x0 = *(const f32x4*)(xb + (g * 16 + n) * 32 + quad * 8);
      const f32x4 x1 = *(const f32x4*)(xb + (g * 16 + n) * 32 + quad * 8 + 4);
      a[g] = cvt8(x0, x1);
    }
#pragma unroll
    for (int i = 0; i < 3; ++i) {
      const f16x8 bf = *(const f16x8*)(wb + (w * 3 + i) * 512 + lane * 8);
      acc[0][i] = MFMA32(a[0], bf, acc[0][i]);
      acc[1][i] = MFMA32(a[1], bf, acc[1][i]);
    }
    __syncthreads();  // drains next chunk's DMA; orders LDS buffer reuse
  }

  const float* bias_p[3] = {bq, bk, bv};
#pragma unroll
  for (int i = 0; i < 3; ++i) {
    const int mt = w * 3 + i;
    const int mat = mt >> 2, tile = mt & 3;
    const int d = tile * 16 + n;
    const float bias = bias_p[mat][d];
#pragma unroll
    for (int g = 0; g < 2; ++g) {
      const int r0 = rowbase + g * 16 + quad * 4;  // C-layout: row=quad*4+r, col=n
      f32x4 aa = acc[g][i];
      if (mat == 0) {
#pragma unroll
        for (int r = 0; r < 4; ++r)
          qs[(size_t)(r0 + r) * DDIM + d] = (f16)((aa[r] + bias) * QSCALE);
      } else if (mat == 1) {
#pragma unroll
        for (int r = 0; r < 4; ++r)
          ks[(size_t)(r0 + r) * DDIM + d] = (f16)(aa[r] + bias);
      } else {
        const int bb = r0 >> 12;
        const int t = r0 & (SEQ - 1);
        *(f16x4*)(vT + (size_t)(bb * 64 + d) * SEQ + t) =
            cvt4(aa[0] + bias, aa[1] + bias, aa[2] + bias, aa[3] + bias);
      }
    }
  }
}

// ---------------- flash attention: transposed softmax, P stays in registers ----
// S' = K·Q^T (C-layout row=key, col=q). PV uses mfma_16x16x16: its B-fragment
// layout [k=quad*4+j][n] IS the S' C-layout -> no LDS round-trip for P.
template <int NSPLIT>
__global__ __launch_bounds__(256, 4) void attn_kernel(const f16* __restrict__ qs,
                                                      const f16* __restrict__ ks,
                                                      const f16* __restrict__ vT,
                                                      float* __restrict__ outp,
                                                      f16* __restrict__ pacc,
                                                      float* __restrict__ pm,
                                                      float* __restrict__ pl) {
  __shared__ __attribute__((aligned(16))) f16 lk[64][SPA];  // [key][d]
  __shared__ __attribute__((aligned(16))) f16 lv[64][SPA];  // [d][key]
  const int tid = threadIdx.x, lane = tid & 63, w = tid >> 6;
  const int n = lane & 15, quad = lane >> 4;
  const int split = blockIdx.x % NSPLIT;
  const int rowblk = blockIdx.x / NSPLIT;
  const int row0 = rowblk * 128 + w * 32;
  const int bb = row0 >> 12;
  const int kbase = split * (SEQ / NSPLIT);
  const int NC = SEQ / NSPLIT / 64;

  const f16* kb = ks + (size_t)bb * SEQ * DDIM;
  const f16* vb = vT + (size_t)bb * DDIM * SEQ;

  const int srow = tid >> 2;          // 0..63
  const int scol = (tid & 3) * 16;    // 0,16,32,48
  const f16* kgp = kb + (size_t)(kbase + srow) * DDIM + scol;
  const f16* vgp = vb + (size_t)srow * SEQ + kbase + scol;

  // persistent Q B-fragments (16x16x32): B[k=d=quad*8+j][col=q=n]
  f16x8 qf[2][2];
#pragma unroll
  for (int g = 0; g < 2; ++g)
#pragma unroll
    for (int hh = 0; hh < 2; ++hh)
      qf[g][hh] = *(const f16x8*)(qs + (size_t)(row0 + g * 16 + n) * DDIM + hh * 32 + quad * 8);

  f32x4 acc[2][4];
  float m[2] = {-1e30f, -1e30f}, ll[2] = {0.f, 0.f};
#pragma unroll
  for (int g = 0; g < 2; ++g)
#pragma unroll
    for (int t = 0; t < 4; ++t) acc[g][t] = (f32x4){0.f, 0.f, 0.f, 0.f};

  f16x8 kr0, kr1, vr0, vr1;
  auto gload = [&](int c) {
    const f16* kp = kgp + (size_t)c * 64 * DDIM;
    kr0 = *(const f16x8*)kp;
    kr1 = *(const f16x8*)(kp + 8);
    const f16* vp = vgp + c * 64;
    vr0 = *(const f16x8*)vp;
    vr1 = *(const f16x8*)(vp + 8);
  };

  gload(0);
  for (int c = 0; c < NC; ++c) {
    *(f16x8*)&lk[srow][scol] = kr0;
    *(f16x8*)&lk[srow][scol + 8] = kr1;
    *(f16x8*)&lv[srow][scol] = vr0;
    *(f16x8*)&lv[srow][scol + 8] = vr1;
    __syncthreads();
    if (c + 1 < NC) gload(c + 1);  // prefetch; drained by end-of-chunk barrier

    // S' = K·Q^T
    f32x4 s[2][4];
#pragma unroll
    for (int st = 0; st < 4; ++st) {
      const f16x8 klo = *(const f16x8*)&lk[st * 16 + n][quad * 8];
      const f16x8 khi = *(const f16x8*)&lk[st * 16 + n][32 + quad * 8];
#pragma unroll
      for (int g = 0; g < 2; ++g) {
        f32x4 z = (f32x4){0.f, 0.f, 0.f, 0.f};
        z = MFMA32(klo, qf[g][0], z);
        s[g][st] = MFMA32(khi, qf[g][1], z);
      }
    }

    // per-lane online softmax; P packed directly as 16x16x16 B-fragments
    f16x4 pq[2][4];
#pragma unroll
    for (int g = 0; g < 2; ++g) {
      f32x4 mx;
#pragma unroll
      for (int r = 0; r < 4; ++r)
        mx[r] = fmaxf(fmaxf(s[g][0][r], s[g][1][r]), fmaxf(s[g][2][r], s[g][3][r]));
      float mloc = fmaxf(fmaxf(mx[0], mx[1]), fmaxf(mx[2], mx[3]));
      mloc = fmaxf(mloc, __shfl_xor(mloc, 16));
      mloc = fmaxf(mloc, __shfl_xor(mloc, 32));
      const float mnew = fmaxf(m[g], mloc);
      const float alpha = __builtin_amdgcn_exp2f(m[g] - mnew);
      m[g] = mnew;
      float psum = 0.f;
#pragma unroll
      for (int st = 0; st < 4; ++st) {
        f32x4 p;
#pragma unroll
        for (int r = 0; r < 4; ++r) p[r] = __builtin_amdgcn_exp2f(s[g][st][r] - mnew);
        psum += (p[0] + p[1]) + (p[2] + p[3]);
        pq[g][st] = cvt4(p[0], p[1], p[2], p[3]);
      }
      ll[g] = ll[g] * alpha + psum;
#pragma unroll
      for (int t = 0; t < 4; ++t) acc[g][t] *= alpha;
    }

    // O^T += V^T·P^T : A = V^T frag [m=d][k=key quad*4+j], B = pq (in-register)
#pragma unroll
    for (int t = 0; t < 4; ++t)
#pragma unroll
      for (int st = 0; st < 4; ++st) {
        const f16x4 va = *(const f16x4*)&lv[t * 16 + n][st * 16 + quad * 4];
        acc[0][t] = MFMA16(va, pq[0][st], acc[0][t]);
        acc[1][t] = MFMA16(va, pq[1][st], acc[1][t]);
      }
    __syncthreads();
  }

  float lred[2];
#pragma unroll
  for (int g = 0; g < 2; ++g) {
    float l = ll[g];
    l += __shfl_xor(l, 16);
    l += __shfl_xor(l, 32);
    lred[g] = l;
  }

  if (NSPLIT == 1) {
#pragma unroll
    for (int g = 0; g < 2; ++g) {
      const float inv = 1.0f / lred[g];
      const int q = row0 + g * 16 + n;
#pragma unroll
      for (int t = 0; t < 4; ++t) {
        f32x4 o = acc[g][t];
#pragma unroll
        for (int r = 0; r < 4; ++r) o[r] *= inv;
        *(f32x4*)(outp + (size_t)q * DDIM + t * 16 + quad * 4) = o;
      }
    }
  } else {
#pragma unroll
    for (int g = 0; g < 2; ++g) {
      const int q = row0 + g * 16 + n;
#pragma unroll
      for (int t = 0; t < 4; ++t)
        *(f16x4*)(pacc + ((size_t)split * NROW + q) * DDIM + t * 16 + quad * 4) =
            cvt4(acc[g][t][0], acc[g][t][1], acc[g][t][2], acc[g][t][3]);
      if (quad == 0) {
        pm[split * NROW + q] = m[g];
        pl[split * NROW + q] = lred[g];
      }
    }
  }
}

// ---------------- split-K combine (f16 partials) ----------------
template <int NSPLIT>
__global__ __launch_bounds__(256) void combine_kernel(const f16* __restrict__ pacc,
                                                      const float* __restrict__ pm,
                                                      const float* __restrict__ pl,
                                                      float* __restrict__ out) {
  const int idx = blockIdx.x * 256 + threadIdx.x;  // NROW*16 units
  const int row = idx >> 4;
  const int c = (idx & 15) * 4;
  float mm = pm[row];
#pragma unroll
  for (int s = 1; s < NSPLIT; ++s) mm = fmaxf(mm, pm[s * NROW + row]);
  float L = 0.f;
  f32x4 o = (f32x4){0.f, 0.f, 0.f, 0.f};
#pragma unroll
  for (int s = 0; s < NSPLIT; ++s) {
    const float e = __builtin_amdgcn_exp2f(pm[s * NROW + row] - mm);
    L += pl[s * NROW + row] * e;
    const f16x4 a = *(const f16x4*)(pacc + ((size_t)s * NROW + row) * DDIM + c);
#pragma unroll
    for (int j = 0; j < 4; ++j) o[j] += (float)a[j] * e;
  }
  const float inv = 1.0f / L;
#pragma unroll
  for (int j = 0; j < 4; ++j) o[j] *= inv;
  *(f32x4*)(out + (size_t)row * DDIM + c) = o;
}

extern "C" void kernel_launch(void* const* d_in, const int* in_sizes, int n_in,
                              void* d_out, int out_size, void* d_ws, size_t ws_size,
                              hipStream_t stream) {
  const float* x  = (const float*)d_in[0];
  const float* Wq = (const float*)d_in[1];
  const float* bq = (const float*)d_in[2];
  const float* Wk = (const float*)d_in[3];
  const float* bk = (const float*)d_in[4];
  const float* Wv = (const float*)d_in[5];
  const float* bv = (const float*)d_in[6];
  float* out = (float*)d_out;

  f16* wf2 = (f16*)d_ws;                      // 3*64*1024 f16, shuffled layout
  f16* qs = wf2 + 3 * 65536;
  f16* ks = qs + (size_t)NROW * DDIM;
  f16* vT = ks + (size_t)NROW * DDIM;
  f16* pacc = vT + (size_t)NROW * DDIM;       // [NSPL][NROW][64] f16
  float* pm = (float*)(pacc + (size_t)NSPL * NROW * DDIM);
  float* pl = pm + (size_t)NSPL * NROW;
  const size_t need = (size_t)((char*)(pl + (size_t)NSPL * NROW) - (char*)d_ws);

  prep_w_kernel<<<dim3(96), dim3(256), 0, stream>>>(Wq, Wk, Wv, wf2);
  proj_kernel<<<dim3(512), dim3(256), 0, stream>>>(x, wf2, bq, bk, bv, qs, ks, vT);

  if (ws_size >= need) {
    attn_kernel<NSPL><<<dim3(128 * NSPL), dim3(256), 0, stream>>>(qs, ks, vT, nullptr, pacc, pm, pl);
    combine_kernel<NSPL><<<dim3(NROW * 16 / 256), dim3(256), 0, stream>>>(pacc, pm, pl, out);
  } else {
    attn_kernel<1><<<dim3(128), dim3(256), 0, stream>>>(qs, ks, vT, out, nullptr, nullptr, nullptr);
  }
}

// Round 11
// 161.788 us; speedup vs baseline: 1.1949x; 1.0178x over previous
//
#include <hip/hip_runtime.h>

#define BATCH 4
#define SEQ   4096
#define CDIM  1024
#define DDIM  64
#define NROW  (BATCH * SEQ)   // 16384
#define NSPL  8

typedef _Float16 f16;
typedef _Float16 f16x8 __attribute__((ext_vector_type(8)));
typedef _Float16 f16x4 __attribute__((ext_vector_type(4)));
typedef __fp16   h16x2 __attribute__((ext_vector_type(2)));  // cvt_pkrtz return type
typedef float    f32x4 __attribute__((ext_vector_type(4)));

#define MFMA32(a, b, c) __builtin_amdgcn_mfma_f32_16x16x32_f16((a), (b), (c), 0, 0, 0)
#define MFMA16(a, b, c) __builtin_amdgcn_mfma_f32_16x16x16f16((a), (b), (c), 0, 0, 0)

// async global->LDS DMA, 16 B per lane; LDS dest = wave-uniform base + lane*16
#define GLDS(g, l)                                                            \
  __builtin_amdgcn_global_load_lds((const __attribute__((address_space(1))) void*)(g), \
                                   (__attribute__((address_space(3))) void*)(l), 16, 0, 0)

// scores = (q·k)*8 (the /scale bug); softmax in exp2 domain => fold 8*log2(e) into q
#define QSCALE 11.5415603f

__device__ inline f16x8 cvt8(f32x4 a, f32x4 b) {
  h16x2 p0 = __builtin_amdgcn_cvt_pkrtz(a[0], a[1]);
  h16x2 p1 = __builtin_amdgcn_cvt_pkrtz(a[2], a[3]);
  h16x2 p2 = __builtin_amdgcn_cvt_pkrtz(b[0], b[1]);
  h16x2 p3 = __builtin_amdgcn_cvt_pkrtz(b[2], b[3]);
  f16x8 r;
  r[0] = p0[0]; r[1] = p0[1]; r[2] = p1[0]; r[3] = p1[1];
  r[4] = p2[0]; r[5] = p2[1]; r[6] = p3[0]; r[7] = p3[1];
  return r;
}

__device__ inline f16x4 cvt4(float a, float b, float c, float d) {
  h16x2 lo = __builtin_amdgcn_cvt_pkrtz(a, b);
  h16x2 hi = __builtin_amdgcn_cvt_pkrtz(c, d);
  f16x4 r;
  r[0] = lo[0]; r[1] = lo[1]; r[2] = hi[0]; r[3] = hi[1];
  return r;
}

// ---------------- W prep: fp32 -> f16, shuffled into per-chunk DMA order ------
// wf2 slot s = ck*12 + mt (ck 0..31 = 32-ch chunk, mt = mat*4+tile), 512 f16.
__global__ __launch_bounds__(256) void prep_w_kernel(const float* __restrict__ Wq,
                                                     const float* __restrict__ Wk,
                                                     const float* __restrict__ Wv,
                                                     f16* __restrict__ wf2) {
  const int t = blockIdx.x * 256 + threadIdx.x;  // 96 blocks -> 24576 threads
  const int lane = t & 63;
  const int s = t >> 6;                // 0..383
  const int mt = s % 12, ck = s / 12;
  const int mat = mt >> 2, tile = mt & 3;
  const int n = lane & 15, quad = lane >> 4;
  const float* W = (mat == 0) ? Wq : (mat == 1) ? Wk : Wv;
  const float* src = W + (size_t)(tile * 16 + n) * CDIM + ck * 32 + quad * 8;
  const f32x4 a = *(const f32x4*)src;
  const f32x4 b = *(const f32x4*)(src + 4);
  *(f16x8*)(wf2 + (size_t)t * 8) = cvt8(a, b);
}

// ---------------- fused QKV projection: 512-thr DMA pipeline ------------------
// 512 blocks x 8 waves, 32 rows/block, full K. Wave (rw=w&1, wc=w>>1): 16 rows,
// 48 cols (mt slots wc*3..+2). 16 DMA instrs/chunk spread over 8 waves (2 each)
// -> 16 waves/CU issuing (the round-10 limiter). Double-buffered 32 KB LDS.
// Outputs: qs plain; ks with 16B-block swizzle (^t&7); v chunk-major 8KB tiles
// with 8B-subblock swizzle (^d&15) so attn can DMA them contiguously.
__global__ __launch_bounds__(512, 4) void proj_kernel(const float* __restrict__ x,
                                                      const f16* __restrict__ wf2,
                                                      const float* __restrict__ bq,
                                                      const float* __restrict__ bk,
                                                      const float* __restrict__ bv,
                                                      f16* __restrict__ qs,
                                                      f16* __restrict__ ks,
                                                      f16* __restrict__ vc) {
  __shared__ __attribute__((aligned(16))) char pbuf[2][16384];  // [x 4K | w 12K]
  const int tid = threadIdx.x, lane = tid & 63, w = tid >> 6;
  const int n = lane & 15, quad = lane >> 4;
  const int rw = w & 1, wc = w >> 1;
  const int rowbase = blockIdx.x * 32;

  // DMA roles: global instr ids i0, i0+1; ids 0-3 = x (4 KB), 4-15 = W (12 KB)
  const int i0 = 2 * w;
  const float* xs0 = x + (size_t)(rowbase + i0 * 8 + (lane >> 3)) * CDIM + (lane & 7) * 4;
  const float* xs1 = xs0 + 8 * CDIM;
  const int wi = (i0 >= 4) ? (i0 - 4) : 0;
  const f16* ws0 = wf2 + (size_t)wi * 512 + lane * 8;
  const f16* ws1 = ws0 + 512;

  f32x4 acc[3];
#pragma unroll
  for (int i = 0; i < 3; ++i) acc[i] = (f32x4){0.f, 0.f, 0.f, 0.f};

  auto issue = [&](int ck, int buf) {
    char* base = &pbuf[buf][0];
    if (i0 < 4) {
      GLDS(xs0 + ck * 32, base + i0 * 1024);
      GLDS(xs1 + ck * 32, base + (i0 + 1) * 1024);
    } else {
      GLDS(ws0 + (size_t)ck * 6144, base + 4096 + (i0 - 4) * 1024);
      GLDS(ws1 + (size_t)ck * 6144, base + 4096 + (i0 - 3) * 1024);
    }
  };

  issue(0, 0);
  for (int ck = 0; ck < 32; ++ck) {
    const int b = ck & 1;
    __syncthreads();                       // drains chunk ck's DMA
    if (ck + 1 < 32) issue(ck + 1, b ^ 1); // overlaps with compute below
    const float* xb = (const float*)&pbuf[b][0];
    const f16* wb = (const f16*)&pbuf[b][4096];
    const f32x4 x0 = *(const f32x4*)(xb + (rw * 16 + n) * 32 + quad * 8);
    const f32x4 x1 = *(const f32x4*)(xb + (rw * 16 + n) * 32 + quad * 8 + 4);
    const f16x8 a = cvt8(x0, x1);
#pragma unroll
    for (int i = 0; i < 3; ++i) {
      const f16x8 bf = *(const f16x8*)(wb + (wc * 3 + i) * 512 + lane * 8);
      acc[i] = MFMA32(a, bf, acc[i]);
    }
  }

  const float* bias_p[3] = {bq, bk, bv};
#pragma unroll
  for (int i = 0; i < 3; ++i) {
    const int mt = wc * 3 + i;
    const int mat = mt >> 2, tile = mt & 3;
    const int d = tile * 16 + n;
    const float bias = bias_p[mat][d];
    const int r0 = rowbase + rw * 16 + quad * 4;  // C-layout: row=quad*4+r, col=n
    const f32x4 aa = acc[i];
    if (mat == 0) {
#pragma unroll
      for (int r = 0; r < 4; ++r)
        qs[(size_t)(r0 + r) * DDIM + d] = (f16)((aa[r] + bias) * QSCALE);
    } else if (mat == 1) {
      // K swizzle: 8-f16 block (d>>3) stored at (d>>3)^(t&7)
#pragma unroll
      for (int r = 0; r < 4; ++r) {
        const int t = r0 + r;
        const int col = ((((d >> 3) ^ (t & 7)) << 3) | (n & 7));
        ks[(size_t)t * DDIM + col] = (f16)(aa[r] + bias);
      }
    } else {
      // V chunk-major tile [bb*64+ck][d][64 keys], 4-key subblock b stored at b^(d&15)
      const int bb = r0 >> 12;
      const int tl = r0 & (SEQ - 1);
      const int ck2 = tl >> 6;
      const int bsw = (((tl & 63) >> 2) ^ n) << 2;  // d&15 == n
      *(f16x4*)(vc + ((size_t)(bb * 64 + ck2) * 64 + d) * 64 + bsw) =
          cvt4(aa[0] + bias, aa[1] + bias, aa[2] + bias, aa[3] + bias);
    }
  }
}

// ---------------- flash attention: DMA-staged K/V, dbuf, 1 barrier/chunk ------
// S' = K·Q^T (C-layout row=key, col=q), per-lane softmax, P stays in registers
// as 16x16x16 B-fragments. K/V tiles DMA'd contiguously (8 KB each) into
// unpadded LDS; swizzled global layouts make fragment reads phase-optimal.
template <int NSPLIT>
__global__ __launch_bounds__(256, 4) void attn_kernel(const f16* __restrict__ qs,
                                                      const f16* __restrict__ ks,
                                                      const f16* __restrict__ vc,
                                                      float* __restrict__ outp,
                                                      f16* __restrict__ pacc,
                                                      float* __restrict__ pm,
                                                      float* __restrict__ pl) {
  __shared__ __attribute__((aligned(16))) f16 lk[2][4096];  // [buf][key][64 d swz]
  __shared__ __attribute__((aligned(16))) f16 lv[2][4096];  // [buf][d][64 key swz]
  const int tid = threadIdx.x, lane = tid & 63, w = tid >> 6;
  const int n = lane & 15, quad = lane >> 4;
  const int split = blockIdx.x % NSPLIT;
  const int rowblk = blockIdx.x / NSPLIT;
  const int row0 = rowblk * 128 + w * 32;
  const int bb = row0 >> 12;
  const int kbase = split * (SEQ / NSPLIT);
  const int kc0 = kbase >> 6;
  const int NC = SEQ / NSPLIT / 64;

  const f16* ksb = ks + (size_t)bb * SEQ * DDIM;
  const f16* vcb = vc + (size_t)bb * 64 * 4096;

  auto issue = [&](int c, int buf) {
#pragma unroll
    for (int i = 0; i < 2; ++i) {
      const int id = 2 * w + i;
      GLDS(ksb + (size_t)(kbase + c * 64) * 64 + id * 512 + lane * 8, &lk[buf][id * 512]);
      GLDS(vcb + (size_t)(kc0 + c) * 4096 + id * 512 + lane * 8, &lv[buf][id * 512]);
    }
  };

  // persistent Q B-fragments (16x16x32): B[k=d=quad*8+j][col=q=n]
  f16x8 qf[2][2];
#pragma unroll
  for (int g = 0; g < 2; ++g)
#pragma unroll
    for (int hh = 0; hh < 2; ++hh)
      qf[g][hh] = *(const f16x8*)(qs + (size_t)(row0 + g * 16 + n) * DDIM + hh * 32 + quad * 8);

  // swizzle read offsets (per-lane constants)
  const int kswz = (quad ^ (n & 7)) << 3;          // klo block; khi = kswz ^ 32
  int vswz[4];
#pragma unroll
  for (int st = 0; st < 4; ++st) vswz[st] = ((((st << 2) | quad) ^ n) << 2);

  f32x4 acc[2][4];
  float m[2] = {-1e30f, -1e30f}, ll[2] = {0.f, 0.f};
#pragma unroll
  for (int g = 0; g < 2; ++g)
#pragma unroll
    for (int t = 0; t < 4; ++t) acc[g][t] = (f32x4){0.f, 0.f, 0.f, 0.f};

  issue(0, 0);
  for (int c = 0; c < NC; ++c) {
    const int b = c & 1;
    __syncthreads();                      // drains chunk c's DMA; guards buffers
    if (c + 1 < NC) issue(c + 1, b ^ 1);  // in flight across entire compute phase

    // S' = K·Q^T
    f32x4 s[2][4];
#pragma unroll
    for (int st = 0; st < 4; ++st) {
      const f16* lkr = &lk[b][(st * 16 + n) * 64];
      const f16x8 klo = *(const f16x8*)(lkr + kswz);
      const f16x8 khi = *(const f16x8*)(lkr + (kswz ^ 32));
#pragma unroll
      for (int g = 0; g < 2; ++g) {
        f32x4 z = (f32x4){0.f, 0.f, 0.f, 0.f};
        z = MFMA32(klo, qf[g][0], z);
        s[g][st] = MFMA32(khi, qf[g][1], z);
      }
    }

    // per-lane online softmax; P packed directly as 16x16x16 B-fragments
    f16x4 pq[2][4];
#pragma unroll
    for (int g = 0; g < 2; ++g) {
      f32x4 mx;
#pragma unroll
      for (int r = 0; r < 4; ++r)
        mx[r] = fmaxf(fmaxf(s[g][0][r], s[g][1][r]), fmaxf(s[g][2][r], s[g][3][r]));
      float mloc = fmaxf(fmaxf(mx[0], mx[1]), fmaxf(mx[2], mx[3]));
      mloc = fmaxf(mloc, __shfl_xor(mloc, 16));
      mloc = fmaxf(mloc, __shfl_xor(mloc, 32));
      const float mnew = fmaxf(m[g], mloc);
      const float alpha = __builtin_amdgcn_exp2f(m[g] - mnew);
      m[g] = mnew;
      float psum = 0.f;
#pragma unroll
      for (int st = 0; st < 4; ++st) {
        f32x4 p;
#pragma unroll
        for (int r = 0; r < 4; ++r) p[r] = __builtin_amdgcn_exp2f(s[g][st][r] - mnew);
        psum += (p[0] + p[1]) + (p[2] + p[3]);
        pq[g][st] = cvt4(p[0], p[1], p[2], p[3]);
      }
      ll[g] = ll[g] * alpha + psum;
#pragma unroll
      for (int t = 0; t < 4; ++t) acc[g][t] *= alpha;
    }

    // O^T += V^T·P^T : A = V^T frag [m=d][k=key quad*4+j] (swizzled LDS read)
#pragma unroll
    for (int dt = 0; dt < 4; ++dt) {
      const f16* lvr = &lv[b][(dt * 16 + n) * 64];
#pragma unroll
      for (int st = 0; st < 4; ++st) {
        const f16x4 va = *(const f16x4*)(lvr + vswz[st]);
        acc[0][dt] = MFMA16(va, pq[0][st], acc[0][dt]);
        acc[1][dt] = MFMA16(va, pq[1][st], acc[1][dt]);
      }
    }
  }

  float lred[2];
#pragma unroll
  for (int g = 0; g < 2; ++g) {
    float l = ll[g];
    l += __shfl_xor(l, 16);
    l += __shfl_xor(l, 32);
    lred[g] = l;
  }

  if (NSPLIT == 1) {
#pragma unroll
    for (int g = 0; g < 2; ++g) {
      const float inv = 1.0f / lred[g];
      const int q = row0 + g * 16 + n;
#pragma unroll
      for (int t = 0; t < 4; ++t) {
        f32x4 o = acc[g][t];
#pragma unroll
        for (int r = 0; r < 4; ++r) o[r] *= inv;
        *(f32x4*)(outp + (size_t)q * DDIM + t * 16 + quad * 4) = o;
      }
    }
  } else {
#pragma unroll
    for (int g = 0; g < 2; ++g) {
      const int q = row0 + g * 16 + n;
#pragma unroll
      for (int t = 0; t < 4; ++t)
        *(f16x4*)(pacc + ((size_t)split * NROW + q) * DDIM + t * 16 + quad * 4) =
            cvt4(acc[g][t][0], acc[g][t][1], acc[g][t][2], acc[g][t][3]);
      if (quad == 0) {
        pm[split * NROW + q] = m[g];
        pl[split * NROW + q] = lred[g];
      }
    }
  }
}

// ---------------- split-K combine (f16 partials) ----------------
template <int NSPLIT>
__global__ __launch_bounds__(256) void combine_kernel(const f16* __restrict__ pacc,
                                                      const float* __restrict__ pm,
                                                      const float* __restrict__ pl,
                                                      float* __restrict__ out) {
  const int idx = blockIdx.x * 256 + threadIdx.x;  // NROW*16 units
  const int row = idx >> 4;
  const int c = (idx & 15) * 4;
  float mm = pm[row];
#pragma unroll
  for (int s = 1; s < NSPLIT; ++s) mm = fmaxf(mm, pm[s * NROW + row]);
  float L = 0.f;
  f32x4 o = (f32x4){0.f, 0.f, 0.f, 0.f};
#pragma unroll
  for (int s = 0; s < NSPLIT; ++s) {
    const float e = __builtin_amdgcn_exp2f(pm[s * NROW + row] - mm);
    L += pl[s * NROW + row] * e;
    const f16x4 a = *(const f16x4*)(pacc + ((size_t)s * NROW + row) * DDIM + c);
#pragma unroll
    for (int j = 0; j < 4; ++j) o[j] += (float)a[j] * e;
  }
  const float inv = 1.0f / L;
#pragma unroll
  for (int j = 0; j < 4; ++j) o[j] *= inv;
  *(f32x4*)(out + (size_t)row * DDIM + c) = o;
}

extern "C" void kernel_launch(void* const* d_in, const int* in_sizes, int n_in,
                              void* d_out, int out_size, void* d_ws, size_t ws_size,
                              hipStream_t stream) {
  const float* x  = (const float*)d_in[0];
  const float* Wq = (const float*)d_in[1];
  const float* bq = (const float*)d_in[2];
  const float* Wk = (const float*)d_in[3];
  const float* bk = (const float*)d_in[4];
  const float* Wv = (const float*)d_in[5];
  const float* bv = (const float*)d_in[6];
  float* out = (float*)d_out;

  f16* wf2 = (f16*)d_ws;                      // 3*64*1024 f16, chunk-slot layout
  f16* qs = wf2 + 3 * 65536;
  f16* ks = qs + (size_t)NROW * DDIM;         // block-swizzled
  f16* vc = ks + (size_t)NROW * DDIM;         // chunk-major tiles, swizzled
  f16* pacc = vc + (size_t)NROW * DDIM;       // [NSPL][NROW][64] f16
  float* pm = (float*)(pacc + (size_t)NSPL * NROW * DDIM);
  float* pl = pm + (size_t)NSPL * NROW;
  const size_t need = (size_t)((char*)(pl + (size_t)NSPL * NROW) - (char*)d_ws);

  prep_w_kernel<<<dim3(96), dim3(256), 0, stream>>>(Wq, Wk, Wv, wf2);
  proj_kernel<<<dim3(512), dim3(512), 0, stream>>>(x, wf2, bq, bk, bv, qs, ks, vc);

  if (ws_size >= need) {
    attn_kernel<NSPL><<<dim3(128 * NSPL), dim3(256), 0, stream>>>(qs, ks, vc, nullptr, pacc, pm, pl);
    combine_kernel<NSPL><<<dim3(NROW * 16 / 256), dim3(256), 0, stream>>>(pacc, pm, pl, out);
  } else {
    attn_kernel<1><<<dim3(128), dim3(256), 0, stream>>>(qs, ks, vc, out, nullptr, nullptr, nullptr);
  }
}

// Round 12
// 159.636 us; speedup vs baseline: 1.2110x; 1.0135x over previous
//
#include <hip/hip_runtime.h>

#define BATCH 4
#define SEQ   4096
#define CDIM  1024
#define DDIM  64
#define NROW  (BATCH * SEQ)   // 16384
#define NSPL  8               // attn key-split
#define KS    4               // proj K-split (across blocks)
#define SEG   (NROW * DDIM)   // 1M elements per partial segment

typedef _Float16 f16;
typedef _Float16 f16x8 __attribute__((ext_vector_type(8)));
typedef _Float16 f16x4 __attribute__((ext_vector_type(4)));
typedef __fp16   h16x2 __attribute__((ext_vector_type(2)));  // cvt_pkrtz return type
typedef float    f32x4 __attribute__((ext_vector_type(4)));

#define MFMA32(a, b, c) __builtin_amdgcn_mfma_f32_16x16x32_f16((a), (b), (c), 0, 0, 0)
#define MFMA16(a, b, c) __builtin_amdgcn_mfma_f32_16x16x16f16((a), (b), (c), 0, 0, 0)

// async global->LDS DMA, 16 B per lane; LDS dest = wave-uniform base + lane*16
#define GLDS(g, l)                                                            \
  __builtin_amdgcn_global_load_lds((const __attribute__((address_space(1))) void*)(g), \
                                   (__attribute__((address_space(3))) void*)(l), 16, 0, 0)

// scores = (q·k)*8 (the /scale bug); softmax in exp2 domain => fold 8*log2(e) into q
#define QSCALE 11.5415603f

__device__ inline f16x8 cvt8(f32x4 a, f32x4 b) {
  h16x2 p0 = __builtin_amdgcn_cvt_pkrtz(a[0], a[1]);
  h16x2 p1 = __builtin_amdgcn_cvt_pkrtz(a[2], a[3]);
  h16x2 p2 = __builtin_amdgcn_cvt_pkrtz(b[0], b[1]);
  h16x2 p3 = __builtin_amdgcn_cvt_pkrtz(b[2], b[3]);
  f16x8 r;
  r[0] = p0[0]; r[1] = p0[1]; r[2] = p1[0]; r[3] = p1[1];
  r[4] = p2[0]; r[5] = p2[1]; r[6] = p3[0]; r[7] = p3[1];
  return r;
}

__device__ inline f16x4 cvt4(float a, float b, float c, float d) {
  h16x2 lo = __builtin_amdgcn_cvt_pkrtz(a, b);
  h16x2 hi = __builtin_amdgcn_cvt_pkrtz(c, d);
  f16x4 r;
  r[0] = lo[0]; r[1] = lo[1]; r[2] = hi[0]; r[3] = hi[1];
  return r;
}

// ---------------- W prep: fp32 -> f16, shuffled into per-chunk DMA order ------
// wf2 slot s = ck*12 + mt (ck 0..31 = 32-ch chunk, mt = mat*4+tile), 512 f16.
__global__ __launch_bounds__(256) void prep_w_kernel(const float* __restrict__ Wq,
                                                     const float* __restrict__ Wk,
                                                     const float* __restrict__ Wv,
                                                     f16* __restrict__ wf2) {
  const int t = blockIdx.x * 256 + threadIdx.x;  // 96 blocks -> 24576 threads
  const int lane = t & 63;
  const int s = t >> 6;                // 0..383
  const int mt = s % 12, ck = s / 12;
  const int mat = mt >> 2, tile = mt & 3;
  const int n = lane & 15, quad = lane >> 4;
  const float* W = (mat == 0) ? Wq : (mat == 1) ? Wk : Wv;
  const float* src = W + (size_t)(tile * 16 + n) * CDIM + ck * 32 + quad * 8;
  const f32x4 a = *(const f32x4*)src;
  const f32x4 b = *(const f32x4*)(src + 4);
  *(f16x8*)(wf2 + (size_t)t * 8) = cvt8(a, b);
}

// ---------------- fused QKV projection: K-split-4, 4 blocks/CU DMA pipeline ---
// 1024 blocks = 256 rowblocks x 4 K-splits; 256 thr (4 waves), 64 rows/block,
// 256 channels/block in 8 chunks of 32. W staged bytes drop 2x vs round 11
// (W_total = 1024 x 96 KB = 98 MB). 40 KB LDS -> 4 blocks/CU, 16 issuing waves
// (m97's concurrency regime). Partials written f16, no bias; combine_proj adds
// splits + bias + QSCALE and writes qs/ks(swizzled)/vc(swizzled).
__global__ __launch_bounds__(256, 4) void proj_kernel(const float* __restrict__ x,
                                                      const f16* __restrict__ wf2,
                                                      f16* __restrict__ ppart) {
  __shared__ __attribute__((aligned(16))) char smem[2][20480];  // [x 8K | w 12K]
  const int tid = threadIdx.x, lane = tid & 63, w = tid >> 6;
  const int n = lane & 15, quad = lane >> 4;
  const int rw = w & 1, wc = w >> 1;
  const int rowblk = blockIdx.x >> 2, split = blockIdx.x & 3;
  const int rowbase = rowblk * 64;

  // DMA sources: wave w issues x instrs {2w,2w+1}, W instrs {3w..3w+2}
  const float* xsrc[2];
#pragma unroll
  for (int j = 0; j < 2; ++j) {
    const int i = 2 * w + j;  // 0..7, covers rows i*8..+8, 128 B segments
    xsrc[j] = x + (size_t)(rowbase + i * 8 + (lane >> 3)) * CDIM + split * 256 + (lane & 7) * 4;
  }
  const f16* wsrc[3];
#pragma unroll
  for (int j = 0; j < 3; ++j) {
    const int mt = 3 * w + j;  // 0..11
    wsrc[j] = wf2 + (size_t)(split * 96 + mt) * 512 + lane * 8;  // +ck*12*512 per chunk
  }

  f32x4 acc[2][6];
#pragma unroll
  for (int rt = 0; rt < 2; ++rt)
#pragma unroll
    for (int i = 0; i < 6; ++i) acc[rt][i] = (f32x4){0.f, 0.f, 0.f, 0.f};

  auto issue = [&](int ck, int b) {
    char* base = &smem[b][0];
#pragma unroll
    for (int j = 0; j < 2; ++j)
      GLDS(xsrc[j] + ck * 32, base + (2 * w + j) * 1024);
#pragma unroll
    for (int j = 0; j < 3; ++j)
      GLDS(wsrc[j] + (size_t)ck * 6144, base + 8192 + (3 * w + j) * 1024);
  };

  issue(0, 0);
  for (int ck = 0; ck < 8; ++ck) {
    const int b = ck & 1;
    __syncthreads();                      // drains chunk ck's DMA
    if (ck + 1 < 8) issue(ck + 1, b ^ 1); // in flight across compute
    const char* base = &smem[b][0];
    f16x8 a[2];
#pragma unroll
    for (int rt = 0; rt < 2; ++rt) {
      const int i = rw * 4 + rt * 2 + (n >> 3);
      const float* xp = (const float*)(base + i * 1024 + (n & 7) * 128 + quad * 32);
      a[rt] = cvt8(*(const f32x4*)xp, *(const f32x4*)(xp + 4));
    }
#pragma unroll
    for (int i2 = 0; i2 < 6; ++i2) {
      const f16x8 bf = *(const f16x8*)(base + 8192 + (wc * 6 + i2) * 1024 + lane * 16);
      acc[0][i2] = MFMA32(a[0], bf, acc[0][i2]);
      acc[1][i2] = MFMA32(a[1], bf, acc[1][i2]);
    }
  }

  // epilogue: f16 partials, no bias, final layouts (q plain, k swizzled, v tiles)
#pragma unroll
  for (int i2 = 0; i2 < 6; ++i2) {
    const int mt = wc * 6 + i2;
    const int mat = mt >> 2, tile = mt & 3;
    const int d = tile * 16 + n;
    f16* seg = ppart + ((size_t)mat * KS + split) * SEG;
#pragma unroll
    for (int rt = 0; rt < 2; ++rt) {
      const int r0 = rowbase + rw * 32 + rt * 16 + quad * 4;
      const f32x4 aa = acc[rt][i2];
      if (mat == 0) {
#pragma unroll
        for (int r = 0; r < 4; ++r)
          seg[(size_t)(r0 + r) * DDIM + d] = (f16)aa[r];
      } else if (mat == 1) {
#pragma unroll
        for (int r = 0; r < 4; ++r) {
          const int t = r0 + r;
          const int col = ((((d >> 3) ^ (t & 7)) << 3) | (d & 7));
          seg[(size_t)t * DDIM + col] = (f16)aa[r];
        }
      } else {
        const int bb = r0 >> 12;
        const int tl = r0 & (SEQ - 1);
        const int ck2 = tl >> 6;
        const int bsw = (((tl & 63) >> 2) ^ n) << 2;  // d&15 == n
        *(f16x4*)(seg + ((size_t)(bb * 64 + ck2) * 64 + d) * 64 + bsw) =
            cvt4(aa[0], aa[1], aa[2], aa[3]);
      }
    }
  }
}

// ---------------- proj combine: sum K-splits + bias (+QSCALE for q) -----------
// grid 1536: seg 0=q -> qs, 1=k -> ks, 2=v -> vc. 8 f16/thread, coalesced.
__global__ __launch_bounds__(256) void combine_proj_kernel(const f16* __restrict__ ppart,
                                                           const float* __restrict__ bq,
                                                           const float* __restrict__ bk,
                                                           const float* __restrict__ bv,
                                                           f16* __restrict__ qs,
                                                           f16* __restrict__ ks,
                                                           f16* __restrict__ vc) {
  const int seg = blockIdx.x / 512;
  const int tix = (blockIdx.x - seg * 512) * 256 + threadIdx.x;
  const size_t base = (size_t)tix * 8;
  const f16* pp = ppart + (size_t)seg * KS * SEG + base;

  float s[8];
#pragma unroll
  for (int j = 0; j < 8; ++j) s[j] = 0.f;
#pragma unroll
  for (int sp = 0; sp < KS; ++sp) {
    const f16x8 v = *(const f16x8*)(pp + (size_t)sp * SEG);
#pragma unroll
    for (int j = 0; j < 8; ++j) s[j] += (float)v[j];
  }

  f16x8 o;
  if (seg == 0) {
    const int d0 = (int)(base & 63);
#pragma unroll
    for (int j = 0; j < 8; ++j) o[j] = (f16)((s[j] + bq[d0 + j]) * QSCALE);
    *(f16x8*)(qs + base) = o;
  } else if (seg == 1) {
    const int t = (int)(base >> 6);
    const int d0 = (((int)(base & 63) >> 3) ^ (t & 7)) << 3;
#pragma unroll
    for (int j = 0; j < 8; ++j) o[j] = (f16)(s[j] + bk[d0 + j]);
    *(f16x8*)(ks + base) = o;
  } else {
    const float b = bv[(int)(base >> 6) & 63];
#pragma unroll
    for (int j = 0; j < 8; ++j) o[j] = (f16)(s[j] + b);
    *(f16x8*)(vc + base) = o;
  }
}

// ---------------- flash attention: DMA-staged K/V, dbuf, 1 barrier/chunk ------
// S' = K·Q^T (C-layout row=key, col=q), per-lane softmax, P stays in registers
// as 16x16x16 B-fragments. K/V tiles DMA'd contiguously (8 KB each) into
// unpadded LDS; swizzled global layouts make fragment reads phase-optimal.
template <int NSPLIT>
__global__ __launch_bounds__(256, 4) void attn_kernel(const f16* __restrict__ qs,
                                                      const f16* __restrict__ ks,
                                                      const f16* __restrict__ vc,
                                                      float* __restrict__ outp,
                                                      f16* __restrict__ pacc,
                                                      float* __restrict__ pm,
                                                      float* __restrict__ pl) {
  __shared__ __attribute__((aligned(16))) f16 lk[2][4096];  // [buf][key][64 d swz]
  __shared__ __attribute__((aligned(16))) f16 lv[2][4096];  // [buf][d][64 key swz]
  const int tid = threadIdx.x, lane = tid & 63, w = tid >> 6;
  const int n = lane & 15, quad = lane >> 4;
  const int split = blockIdx.x % NSPLIT;
  const int rowblk = blockIdx.x / NSPLIT;
  const int row0 = rowblk * 128 + w * 32;
  const int bb = row0 >> 12;
  const int kbase = split * (SEQ / NSPLIT);
  const int kc0 = kbase >> 6;
  const int NC = SEQ / NSPLIT / 64;

  const f16* ksb = ks + (size_t)bb * SEQ * DDIM;
  const f16* vcb = vc + (size_t)bb * 64 * 4096;

  auto issue = [&](int c, int buf) {
#pragma unroll
    for (int i = 0; i < 2; ++i) {
      const int id = 2 * w + i;
      GLDS(ksb + (size_t)(kbase + c * 64) * 64 + id * 512 + lane * 8, &lk[buf][id * 512]);
      GLDS(vcb + (size_t)(kc0 + c) * 4096 + id * 512 + lane * 8, &lv[buf][id * 512]);
    }
  };

  // persistent Q B-fragments (16x16x32): B[k=d=quad*8+j][col=q=n]
  f16x8 qf[2][2];
#pragma unroll
  for (int g = 0; g < 2; ++g)
#pragma unroll
    for (int hh = 0; hh < 2; ++hh)
      qf[g][hh] = *(const f16x8*)(qs + (size_t)(row0 + g * 16 + n) * DDIM + hh * 32 + quad * 8);

  // swizzle read offsets (per-lane constants)
  const int kswz = (quad ^ (n & 7)) << 3;          // klo block; khi = kswz ^ 32
  int vswz[4];
#pragma unroll
  for (int st = 0; st < 4; ++st) vswz[st] = ((((st << 2) | quad) ^ n) << 2);

  f32x4 acc[2][4];
  float m[2] = {-1e30f, -1e30f}, ll[2] = {0.f, 0.f};
#pragma unroll
  for (int g = 0; g < 2; ++g)
#pragma unroll
    for (int t = 0; t < 4; ++t) acc[g][t] = (f32x4){0.f, 0.f, 0.f, 0.f};

  issue(0, 0);
  for (int c = 0; c < NC; ++c) {
    const int b = c & 1;
    __syncthreads();                      // drains chunk c's DMA; guards buffers
    if (c + 1 < NC) issue(c + 1, b ^ 1);  // in flight across entire compute phase

    // S' = K·Q^T
    f32x4 s[2][4];
#pragma unroll
    for (int st = 0; st < 4; ++st) {
      const f16* lkr = &lk[b][(st * 16 + n) * 64];
      const f16x8 klo = *(const f16x8*)(lkr + kswz);
      const f16x8 khi = *(const f16x8*)(lkr + (kswz ^ 32));
#pragma unroll
      for (int g = 0; g < 2; ++g) {
        f32x4 z = (f32x4){0.f, 0.f, 0.f, 0.f};
        z = MFMA32(klo, qf[g][0], z);
        s[g][st] = MFMA32(khi, qf[g][1], z);
      }
    }

    // per-lane online softmax; P packed directly as 16x16x16 B-fragments
    f16x4 pq[2][4];
#pragma unroll
    for (int g = 0; g < 2; ++g) {
      f32x4 mx;
#pragma unroll
      for (int r = 0; r < 4; ++r)
        mx[r] = fmaxf(fmaxf(s[g][0][r], s[g][1][r]), fmaxf(s[g][2][r], s[g][3][r]));
      float mloc = fmaxf(fmaxf(mx[0], mx[1]), fmaxf(mx[2], mx[3]));
      mloc = fmaxf(mloc, __shfl_xor(mloc, 16));
      mloc = fmaxf(mloc, __shfl_xor(mloc, 32));
      const float mnew = fmaxf(m[g], mloc);
      const float alpha = __builtin_amdgcn_exp2f(m[g] - mnew);
      m[g] = mnew;
      float psum = 0.f;
#pragma unroll
      for (int st = 0; st < 4; ++st) {
        f32x4 p;
#pragma unroll
        for (int r = 0; r < 4; ++r) p[r] = __builtin_amdgcn_exp2f(s[g][st][r] - mnew);
        psum += (p[0] + p[1]) + (p[2] + p[3]);
        pq[g][st] = cvt4(p[0], p[1], p[2], p[3]);
      }
      ll[g] = ll[g] * alpha + psum;
#pragma unroll
      for (int t = 0; t < 4; ++t) acc[g][t] *= alpha;
    }

    // O^T += V^T·P^T : A = V^T frag [m=d][k=key quad*4+j] (swizzled LDS read)
#pragma unroll
    for (int dt = 0; dt < 4; ++dt) {
      const f16* lvr = &lv[b][(dt * 16 + n) * 64];
#pragma unroll
      for (int st = 0; st < 4; ++st) {
        const f16x4 va = *(const f16x4*)(lvr + vswz[st]);
        acc[0][dt] = MFMA16(va, pq[0][st], acc[0][dt]);
        acc[1][dt] = MFMA16(va, pq[1][st], acc[1][dt]);
      }
    }
  }

  float lred[2];
#pragma unroll
  for (int g = 0; g < 2; ++g) {
    float l = ll[g];
    l += __shfl_xor(l, 16);
    l += __shfl_xor(l, 32);
    lred[g] = l;
  }

  if (NSPLIT == 1) {
#pragma unroll
    for (int g = 0; g < 2; ++g) {
      const float inv = 1.0f / lred[g];
      const int q = row0 + g * 16 + n;
#pragma unroll
      for (int t = 0; t < 4; ++t) {
        f32x4 o = acc[g][t];
#pragma unroll
        for (int r = 0; r < 4; ++r) o[r] *= inv;
        *(f32x4*)(outp + (size_t)q * DDIM + t * 16 + quad * 4) = o;
      }
    }
  } else {
#pragma unroll
    for (int g = 0; g < 2; ++g) {
      const int q = row0 + g * 16 + n;
#pragma unroll
      for (int t = 0; t < 4; ++t)
        *(f16x4*)(pacc + ((size_t)split * NROW + q) * DDIM + t * 16 + quad * 4) =
            cvt4(acc[g][t][0], acc[g][t][1], acc[g][t][2], acc[g][t][3]);
      if (quad == 0) {
        pm[split * NROW + q] = m[g];
        pl[split * NROW + q] = lred[g];
      }
    }
  }
}

// ---------------- attn split-K combine (f16 partials) ----------------
template <int NSPLIT>
__global__ __launch_bounds__(256) void combine_kernel(const f16* __restrict__ pacc,
                                                      const float* __restrict__ pm,
                                                      const float* __restrict__ pl,
                                                      float* __restrict__ out) {
  const int idx = blockIdx.x * 256 + threadIdx.x;  // NROW*16 units
  const int row = idx >> 4;
  const int c = (idx & 15) * 4;
  float mm = pm[row];
#pragma unroll
  for (int s = 1; s < NSPLIT; ++s) mm = fmaxf(mm, pm[s * NROW + row]);
  float L = 0.f;
  f32x4 o = (f32x4){0.f, 0.f, 0.f, 0.f};
#pragma unroll
  for (int s = 0; s < NSPLIT; ++s) {
    const float e = __builtin_amdgcn_exp2f(pm[s * NROW + row] - mm);
    L += pl[s * NROW + row] * e;
    const f16x4 a = *(const f16x4*)(pacc + ((size_t)s * NROW + row) * DDIM + c);
#pragma unroll
    for (int j = 0; j < 4; ++j) o[j] += (float)a[j] * e;
  }
  const float inv = 1.0f / L;
#pragma unroll
  for (int j = 0; j < 4; ++j) o[j] *= inv;
  *(f32x4*)(out + (size_t)row * DDIM + c) = o;
}

extern "C" void kernel_launch(void* const* d_in, const int* in_sizes, int n_in,
                              void* d_out, int out_size, void* d_ws, size_t ws_size,
                              hipStream_t stream) {
  const float* x  = (const float*)d_in[0];
  const float* Wq = (const float*)d_in[1];
  const float* bq = (const float*)d_in[2];
  const float* Wk = (const float*)d_in[3];
  const float* bk = (const float*)d_in[4];
  const float* Wv = (const float*)d_in[5];
  const float* bv = (const float*)d_in[6];
  float* out = (float*)d_out;

  f16* wf2 = (f16*)d_ws;                      // 3*64*1024 f16, chunk-slot layout
  f16* qs = wf2 + 3 * 65536;
  f16* ks = qs + (size_t)SEG;                 // block-swizzled
  f16* vc = ks + (size_t)SEG;                 // chunk-major tiles, swizzled
  f16* ppart = vc + (size_t)SEG;              // [3][KS][SEG] f16 proj partials
  f16* pacc = ppart + (size_t)3 * KS * SEG;   // [NSPL][NROW][64] f16 attn partials
  float* pm = (float*)(pacc + (size_t)NSPL * SEG);
  float* pl = pm + (size_t)NSPL * NROW;
  const size_t need = (size_t)((char*)(pl + (size_t)NSPL * NROW) - (char*)d_ws);

  prep_w_kernel<<<dim3(96), dim3(256), 0, stream>>>(Wq, Wk, Wv, wf2);
  proj_kernel<<<dim3(256 * KS), dim3(256), 0, stream>>>(x, wf2, ppart);
  combine_proj_kernel<<<dim3(1536), dim3(256), 0, stream>>>(ppart, bq, bk, bv, qs, ks, vc);

  if (ws_size >= need) {
    attn_kernel<NSPL><<<dim3(128 * NSPL), dim3(256), 0, stream>>>(qs, ks, vc, nullptr, pacc, pm, pl);
    combine_kernel<NSPL><<<dim3(NROW * 16 / 256), dim3(256), 0, stream>>>(pacc, pm, pl, out);
  } else {
    attn_kernel<1><<<dim3(128), dim3(256), 0, stream>>>(qs, ks, vc, out, nullptr, nullptr, nullptr);
  }
}